// Round 1
// baseline (1551.784 us; speedup 1.0000x reference)
//
#include <hip/hip_runtime.h>
#include <math.h>

// Problem constants
#define BATCH 2
#define SEQLEN 1024
#define DMODEL 1024
#define DINNER 2048
#define NHEADS 32
#define HEADDIM 64
#define DSTATE 64
#define NTOK (BATCH * SEQLEN)          // 2048
#define OUT_ELEMS (BATCH * SEQLEN * DMODEL)  // 2097152

// ---------------------------------------------------------------------------
// Generic f32 GEMM:  C[m,n] = sum_k A[m*K+k] * B[n*K+k]   (A @ B^T)
// ldc == N. M % 64 == 0, K % 16 == 0 assumed; N guarded.
// Tile 64x64, BK=16, 256 threads, 4x4 microtile.
// ---------------------------------------------------------------------------
__global__ __launch_bounds__(256) void gemm_nt(
    const float* __restrict__ A, const float* __restrict__ B,
    float* __restrict__ C, int M, int N, int K) {
  __shared__ __align__(16) float sA[16][64];  // [k][m]
  __shared__ __align__(16) float sB[16][64];  // [k][n]
  const int t = threadIdx.x;
  const int tx = t & 15, ty = t >> 4;
  const int bm = blockIdx.y * 64, bn = blockIdx.x * 64;

  const int lrow = t >> 2;           // 0..63
  const int lk = (t & 3) * 4;        // 0,4,8,12
  const float* Aptr = A + (size_t)(bm + lrow) * K + lk;
  const float* Bptr = B + (size_t)(bn + lrow) * K + lk;
  const bool bvalid = (bn + lrow) < N;

  float acc[4][4];
#pragma unroll
  for (int i = 0; i < 4; ++i)
#pragma unroll
    for (int j = 0; j < 4; ++j) acc[i][j] = 0.f;

  float4 av = *(const float4*)(Aptr);
  float4 bv = bvalid ? *(const float4*)(Bptr) : make_float4(0.f, 0.f, 0.f, 0.f);

  for (int k0 = 0; k0 < K; k0 += 16) {
    __syncthreads();  // protect previous compute reads
    sA[lk + 0][lrow] = av.x; sA[lk + 1][lrow] = av.y;
    sA[lk + 2][lrow] = av.z; sA[lk + 3][lrow] = av.w;
    sB[lk + 0][lrow] = bv.x; sB[lk + 1][lrow] = bv.y;
    sB[lk + 2][lrow] = bv.z; sB[lk + 3][lrow] = bv.w;
    __syncthreads();
    if (k0 + 16 < K) {  // prefetch next tile into regs (hides under compute)
      av = *(const float4*)(Aptr + k0 + 16);
      bv = bvalid ? *(const float4*)(Bptr + k0 + 16) : make_float4(0.f, 0.f, 0.f, 0.f);
    }
#pragma unroll
    for (int kk = 0; kk < 16; ++kk) {
      float4 a4 = *(const float4*)&sA[kk][ty * 4];
      float4 b4 = *(const float4*)&sB[kk][tx * 4];
      float a[4] = {a4.x, a4.y, a4.z, a4.w};
      float bb[4] = {b4.x, b4.y, b4.z, b4.w};
#pragma unroll
      for (int i = 0; i < 4; ++i)
#pragma unroll
        for (int j = 0; j < 4; ++j) acc[i][j] += a[i] * bb[j];
    }
  }

#pragma unroll
  for (int i = 0; i < 4; ++i) {
    const int row = bm + ty * 4 + i;
#pragma unroll
    for (int j = 0; j < 4; ++j) {
      const int col = bn + tx * 4 + j;
      if (col < N) C[(size_t)row * N + col] = acc[i][j];
    }
  }
}

// ---------------------------------------------------------------------------
// Depthwise causal conv (width 4) + bias + SiLU.
// Input: x = xz[tok*4096 + c], c in [0,2048). Output xc[tok*2048+c].
// ---------------------------------------------------------------------------
__global__ __launch_bounds__(256) void conv_silu(
    const float* __restrict__ xz, const float* __restrict__ cw,
    const float* __restrict__ cb, float* __restrict__ xc) {
  const int idx = blockIdx.x * 256 + threadIdx.x;
  if (idx >= NTOK * DINNER) return;
  const int c = idx & (DINNER - 1);
  const int tok = idx >> 11;
  const int l = tok & (SEQLEN - 1);
  const float w0 = cw[c * 4 + 0], w1 = cw[c * 4 + 1];
  const float w2 = cw[c * 4 + 2], w3 = cw[c * 4 + 3];
  const float* xp = xz + (size_t)tok * (2 * DINNER) + c;
  float acc = cb[c] + w3 * xp[0];
  if (l >= 1) acc += w2 * xp[-(2 * DINNER)];
  if (l >= 2) acc += w1 * xp[-2 * (2 * DINNER)];
  if (l >= 3) acc += w0 * xp[-3 * (2 * DINNER)];
  // silu
  xc[idx] = acc / (1.f + expf(-acc));
}

// ---------------------------------------------------------------------------
// dt activation: dt[i] = softplus(dt[i] + dt_b[i%32])   (in-place)
// ---------------------------------------------------------------------------
__global__ __launch_bounds__(256) void dt_act(float* __restrict__ dtb,
                                              const float* __restrict__ dt_b) {
  const int i = blockIdx.x * 256 + threadIdx.x;
  if (i >= NTOK * NHEADS) return;
  const float v = dtb[i] + dt_b[i & (NHEADS - 1)];
  dtb[i] = (v > 20.f) ? v : log1pf(expf(v));
}

// ---------------------------------------------------------------------------
// Sequential selective scan. One block per (b,h). 256 threads.
// Thread t owns p = t&63, n in [ (t>>6)*16, (t>>6)*16+16 ).
// ---------------------------------------------------------------------------
__global__ __launch_bounds__(256) void scan_kernel(
    const float* __restrict__ xc, const float* __restrict__ dtb,
    const float* __restrict__ Bm, const float* __restrict__ Cm,
    const float* __restrict__ A_log, const float* __restrict__ Dvec,
    float* __restrict__ y, float* __restrict__ hf) {
  const int bh = blockIdx.x;
  const int b = bh >> 5, h = bh & (NHEADS - 1);
  const int t = threadIdx.x;
  const int p = t & 63, g = t >> 6;

  __shared__ float sx[64], sB[64], sC[64];
  __shared__ float sdt;
  __shared__ float part[4][64];

  float hreg[16];
#pragma unroll
  for (int j = 0; j < 16; ++j) hreg[j] = 0.f;

  const float Ah = -expf(A_log[h]);
  const float Dh = Dvec[h];
  const size_t base = (size_t)b * SEQLEN * DINNER + h * HEADDIM;
  const float* xp = xc + base;
  const float* Bp = Bm + base;
  const float* Cp = Cm + base;
  const float* dtp = dtb + (size_t)b * SEQLEN * NHEADS + h;
  float* yp = y + base;

  // register prefetch of step l data (role by g)
  float pre;
  {
    if (g == 0) pre = xp[p];
    else if (g == 1) pre = Bp[p];
    else if (g == 2) pre = Cp[p];
    else pre = dtp[0];
  }

  for (int l = 0; l < SEQLEN; ++l) {
    if (g == 0) sx[p] = pre;
    else if (g == 1) sB[p] = pre;
    else if (g == 2) sC[p] = pre;
    else if (p == 0) sdt = pre;
    __syncthreads();
    if (l + 1 < SEQLEN) {
      const size_t o = (size_t)(l + 1) * DINNER;
      if (g == 0) pre = xp[o + p];
      else if (g == 1) pre = Bp[o + p];
      else if (g == 2) pre = Cp[o + p];
      else pre = dtp[(size_t)(l + 1) * NHEADS];
    }
    const float dtv = sdt;
    const float a = expf(Ah * dtv);
    const float xv = sx[p];
    const float coef = dtv * xv;
    float acc = 0.f;
#pragma unroll
    for (int j = 0; j < 16; ++j) {
      const int n = g * 16 + j;
      hreg[j] = a * hreg[j] + coef * sB[n];
      acc += hreg[j] * sC[n];
    }
    part[g][p] = acc;
    __syncthreads();
    if (t < 64) {
      yp[(size_t)l * DINNER + p] =
          part[0][p] + part[1][p] + part[2][p] + part[3][p] + Dh * xv;
    }
  }

  // final state -> d_out tail, layout [B,H,P,N]
  const size_t ho = ((size_t)bh * HEADDIM + p) * DSTATE + g * 16;
#pragma unroll
  for (int j = 0; j < 16; ++j) hf[ho + j] = hreg[j];
}

// ---------------------------------------------------------------------------
// LayerNorm over 2048 + SiLU(z) gate. One block per token.
// ---------------------------------------------------------------------------
__global__ __launch_bounds__(256) void ln_gate(
    const float* __restrict__ y, const float* __restrict__ xz,
    const float* __restrict__ lnw, const float* __restrict__ lnb,
    float* __restrict__ out) {
  const int tok = blockIdx.x;
  const int t = threadIdx.x;
  const float* yr = y + (size_t)tok * DINNER;
  const float* zr = xz + (size_t)tok * (2 * DINNER) + DINNER;

  float v[8];
  float s = 0.f, s2 = 0.f;
#pragma unroll
  for (int i = 0; i < 8; ++i) {
    v[i] = yr[t + i * 256];
    s += v[i];
    s2 += v[i] * v[i];
  }
#pragma unroll
  for (int off = 32; off > 0; off >>= 1) {
    s += __shfl_down(s, off);
    s2 += __shfl_down(s2, off);
  }
  __shared__ float ws[4], ws2[4];
  const int wid = t >> 6;
  if ((t & 63) == 0) { ws[wid] = s; ws2[wid] = s2; }
  __syncthreads();
  const float mean = (ws[0] + ws[1] + ws[2] + ws[3]) * (1.f / DINNER);
  const float m2 = (ws2[0] + ws2[1] + ws2[2] + ws2[3]) * (1.f / DINNER);
  const float rstd = rsqrtf(m2 - mean * mean + 1e-5f);
#pragma unroll
  for (int i = 0; i < 8; ++i) {
    const int c = t + i * 256;
    const float zn = zr[c];
    const float gate = zn / (1.f + expf(-zn));
    out[(size_t)tok * DINNER + c] = ((v[i] - mean) * rstd * lnw[c] + lnb[c]) * gate;
  }
}

// ---------------------------------------------------------------------------
extern "C" void kernel_launch(void* const* d_in, const int* in_sizes, int n_in,
                              void* d_out, int out_size, void* d_ws, size_t ws_size,
                              hipStream_t stream) {
  const float* hidden = (const float*)d_in[0];
  const float* in_proj_w = (const float*)d_in[1];
  const float* conv_w = (const float*)d_in[2];
  const float* conv_b = (const float*)d_in[3];
  const float* A_log = (const float*)d_in[4];
  const float* dt_w = (const float*)d_in[5];
  const float* dt_b = (const float*)d_in[6];
  const float* B_w = (const float*)d_in[7];
  const float* C_w = (const float*)d_in[8];
  const float* Dv = (const float*)d_in[9];
  const float* ln_w = (const float*)d_in[10];
  const float* ln_b = (const float*)d_in[11];
  const float* out_proj_w = (const float*)d_in[12];

  float* out = (float*)d_out;
  float* ws = (float*)d_ws;

  float* xz  = ws;                       // NTOK*4096 = 8M floats
  float* xc  = ws + ((size_t)8 << 20);   // 4M floats
  float* Bm  = ws + ((size_t)12 << 20);  // 4M
  float* Cm  = ws + ((size_t)16 << 20);  // 4M
  float* ysc = ws + ((size_t)20 << 20);  // 4M
  float* dtb = ws + ((size_t)24 << 20);  // 64K
  float* yg  = xc;                       // reuse xc after scan

  float* hf = out + OUT_ELEMS;

  // 1. xz = hidden @ in_proj_w^T   [2048 x 4096], K=1024
  gemm_nt<<<dim3(4096 / 64, NTOK / 64), 256, 0, stream>>>(
      hidden, in_proj_w, xz, NTOK, 2 * DINNER, DMODEL);

  // 2. causal depthwise conv + SiLU -> xc
  conv_silu<<<(NTOK * DINNER) / 256, 256, 0, stream>>>(xz, conv_w, conv_b, xc);

  // 3. dt_raw = xc @ dt_w^T   [2048 x 32], K=2048
  gemm_nt<<<dim3(1, NTOK / 64), 256, 0, stream>>>(xc, dt_w, dtb, NTOK, NHEADS, DINNER);

  // 4. Bm = xc @ B_w^T ; Cm = xc @ C_w^T   [2048 x 2048], K=2048
  gemm_nt<<<dim3(DINNER / 64, NTOK / 64), 256, 0, stream>>>(xc, B_w, Bm, NTOK, DINNER, DINNER);
  gemm_nt<<<dim3(DINNER / 64, NTOK / 64), 256, 0, stream>>>(xc, C_w, Cm, NTOK, DINNER, DINNER);

  // 5. dt = softplus(dt_raw + dt_b)
  dt_act<<<(NTOK * NHEADS) / 256, 256, 0, stream>>>(dtb, dt_b);

  // 6. sequential scan -> ysc, h_final
  scan_kernel<<<BATCH * NHEADS, 256, 0, stream>>>(xc, dtb, Bm, Cm, A_log, Dv, ysc, hf);

  // 7. LN + SiLU(z) gate -> yg
  ln_gate<<<NTOK, 256, 0, stream>>>(ysc, xz, ln_w, ln_b, yg);

  // 8. out = yg @ out_proj_w^T   [2048 x 1024], K=2048
  gemm_nt<<<dim3(DMODEL / 64, NTOK / 64), 256, 0, stream>>>(yg, out_proj_w, out, NTOK, DMODEL, DINNER);
}

// Round 2
// 509.145 us; speedup vs baseline: 3.0478x; 3.0478x over previous
//
#include <hip/hip_runtime.h>
#include <math.h>

#define BATCH 2
#define SEQLEN 1024
#define DMODEL 1024
#define DINNER 2048
#define NHEADS 32
#define HEADDIM 64
#define DSTATE 64
#define NTOK (BATCH * SEQLEN)                 // 2048
#define OUT_ELEMS (BATCH * SEQLEN * DMODEL)   // 2097152

typedef unsigned short bf16u;
typedef __attribute__((ext_vector_type(8))) short short8;
typedef __attribute__((ext_vector_type(4))) float f32x4;

__device__ __forceinline__ float b2f(short u) {
  return __uint_as_float(((unsigned)(unsigned short)u) << 16);
}
__device__ __forceinline__ unsigned short f2b(float f) {
  unsigned u = __float_as_uint(f);
  u += 0x7fff + ((u >> 16) & 1);   // RNE
  return (unsigned short)(u >> 16);
}

__device__ __forceinline__ void gload16(const void* g, void* l) {
  __builtin_amdgcn_global_load_lds(
      (const __attribute__((address_space(1))) unsigned int*)g,
      (__attribute__((address_space(3))) unsigned int*)l, 16, 0, 0);
}

__device__ __forceinline__ void stv(float* p, float v) { *p = v; }
__device__ __forceinline__ void stv(bf16u* p, float v) { *p = f2b(v); }

// ---------------------------------------------------------------------------
// f32 -> bf16 conversion, 8 elems/thread
// ---------------------------------------------------------------------------
__global__ __launch_bounds__(256) void cvt_bf16(const float* __restrict__ in,
                                                bf16u* __restrict__ out, int n) {
  const int i = (blockIdx.x * 256 + threadIdx.x) * 8;
  if (i >= n) return;
  const float4 a = *(const float4*)(in + i);
  const float4 b = *(const float4*)(in + i + 4);
  short8 o;
  o[0] = f2b(a.x); o[1] = f2b(a.y); o[2] = f2b(a.z); o[3] = f2b(a.w);
  o[4] = f2b(b.x); o[5] = f2b(b.y); o[6] = f2b(b.z); o[7] = f2b(b.w);
  *(short8*)(out + i) = o;
}

// ---------------------------------------------------------------------------
// bf16 MFMA GEMM:  C[m,n] = sum_k A[m][k] * B[n][k]   (A@B^T), f32 accum.
// Tile 128x128, BK=32, 256 threads (4 waves, 2x2 of 64x64), m97 structure.
// M,K multiples of 128/32; N guarded (B rows clamped).
// ---------------------------------------------------------------------------
template <typename OutT>
__global__ __launch_bounds__(256) void gemm_mfma(
    const bf16u* __restrict__ A, const bf16u* __restrict__ B,
    OutT* __restrict__ C, int M, int N, int K) {
  __shared__ bf16u sA[128 * 32];
  __shared__ bf16u sB[128 * 32];
  const int t = threadIdx.x;
  const int lane = t & 63, wave = t >> 6;
  const int bm = blockIdx.y * 128, bn = blockIdx.x * 128;
  const int wr = wave >> 1, wc = wave & 1;

  // staging slots s=t and s+256: row = s>>2, kcol = (s&3)*8 (slot = 16B)
  const int ra0 = bm + (t >> 2), ra1 = bm + 64 + (t >> 2);
  int rb0 = bn + (t >> 2), rb1 = bn + 64 + (t >> 2);
  rb0 = rb0 < N ? rb0 : N - 1;
  rb1 = rb1 < N ? rb1 : N - 1;
  const int kc = (t & 3) * 8;

  bf16u* ldsA0 = sA + (wave * 64) * 8;
  bf16u* ldsA1 = sA + (256 + wave * 64) * 8;
  bf16u* ldsB0 = sB + (wave * 64) * 8;
  bf16u* ldsB1 = sB + (256 + wave * 64) * 8;

  const f32x4 zero = {0.f, 0.f, 0.f, 0.f};
  f32x4 acc[4][4];
#pragma unroll
  for (int m = 0; m < 4; ++m)
#pragma unroll
    for (int n = 0; n < 4; ++n) acc[m][n] = zero;

  const int ln15 = lane & 15, kq = lane >> 4;

  for (int k0 = 0; k0 < K; k0 += 32) {
    __syncthreads();
    gload16(A + (size_t)ra0 * K + k0 + kc, ldsA0);
    gload16(A + (size_t)ra1 * K + k0 + kc, ldsA1);
    gload16(B + (size_t)rb0 * K + k0 + kc, ldsB0);
    gload16(B + (size_t)rb1 * K + k0 + kc, ldsB1);
    __syncthreads();
    short8 af[4], bfr[4];
#pragma unroll
    for (int m = 0; m < 4; ++m)
      af[m] = *(const short8*)&sA[(wr * 64 + m * 16 + ln15) * 32 + kq * 8];
#pragma unroll
    for (int n = 0; n < 4; ++n)
      bfr[n] = *(const short8*)&sB[(wc * 64 + n * 16 + ln15) * 32 + kq * 8];
#pragma unroll
    for (int m = 0; m < 4; ++m)
#pragma unroll
      for (int n = 0; n < 4; ++n)
        acc[m][n] = __builtin_amdgcn_mfma_f32_16x16x32_bf16(af[m], bfr[n], acc[m][n], 0, 0, 0);
  }

  const int rbase = bm + wr * 64, cbase = bn + wc * 64;
#pragma unroll
  for (int m = 0; m < 4; ++m) {
#pragma unroll
    for (int n = 0; n < 4; ++n) {
      const int col = cbase + n * 16 + ln15;
      if (col < N) {
#pragma unroll
        for (int r = 0; r < 4; ++r) {
          const int row = rbase + m * 16 + kq * 4 + r;
          stv(&C[(size_t)row * N + col], acc[m][n][r]);
        }
      }
    }
  }
}

// ---------------------------------------------------------------------------
// Depthwise causal conv (width 4) + bias + SiLU. bf16 in; f32 + bf16 out.
// 8 channels per thread.
// ---------------------------------------------------------------------------
__global__ __launch_bounds__(256) void conv_silu(
    const bf16u* __restrict__ xzb, const float* __restrict__ cw,
    const float* __restrict__ cb, float* __restrict__ xc,
    bf16u* __restrict__ xcb) {
  const int i = blockIdx.x * 256 + threadIdx.x;  // 0..512K
  const int c8 = (i & 255) * 8;
  const int tok = i >> 8;
  const int l = tok & (SEQLEN - 1);
  const bf16u* xp = xzb + (size_t)tok * (2 * DINNER) + c8;
  const short8 zer = {0, 0, 0, 0, 0, 0, 0, 0};
  const short8 x0 = *(const short8*)xp;
  const short8 x1 = (l >= 1) ? *(const short8*)(xp - 1 * (2 * DINNER)) : zer;
  const short8 x2 = (l >= 2) ? *(const short8*)(xp - 2 * (2 * DINNER)) : zer;
  const short8 x3 = (l >= 3) ? *(const short8*)(xp - 3 * (2 * DINNER)) : zer;
  float o[8];
  short8 ob;
#pragma unroll
  for (int j = 0; j < 8; ++j) {
    const float4 w = *(const float4*)(cw + (c8 + j) * 4);
    float acc = cb[c8 + j] + w.w * b2f(x0[j]);
    acc += w.z * b2f(x1[j]);
    acc += w.y * b2f(x2[j]);
    acc += w.x * b2f(x3[j]);
    const float s = acc / (1.f + __expf(-acc));
    o[j] = s;
    ob[j] = (short)f2b(s);
  }
  float* xo = xc + (size_t)tok * DINNER + c8;
  *(float4*)(xo + 0) = make_float4(o[0], o[1], o[2], o[3]);
  *(float4*)(xo + 4) = make_float4(o[4], o[5], o[6], o[7]);
  *(short8*)(xcb + (size_t)tok * DINNER + c8) = ob;
}

// ---------------------------------------------------------------------------
// dt activation: softplus(dt + dt_b), in-place f32
// ---------------------------------------------------------------------------
__global__ __launch_bounds__(256) void dt_act(float* __restrict__ dtb,
                                              const float* __restrict__ dt_b) {
  const int i = blockIdx.x * 256 + threadIdx.x;
  if (i >= NTOK * NHEADS) return;
  const float v = dtb[i] + dt_b[i & (NHEADS - 1)];
  dtb[i] = (v > 20.f) ? v : log1pf(expf(v));
}

// ---------------------------------------------------------------------------
// Selective scan. Grid 256 = (b,h,pq); 64 threads (single wave, no barriers
// in steady state). Lane: p = pq*16 + (lane&15), n-chunk = (lane>>4)*16..+16.
// 16-step batches staged in LDS with register prefetch of the next batch.
// ---------------------------------------------------------------------------
#define SCAN_T 16
__global__ __launch_bounds__(64) void scan_kernel(
    const float* __restrict__ xc, const float* __restrict__ dtb,
    const float* __restrict__ Bm, const float* __restrict__ Cm,
    const float* __restrict__ A_log, const float* __restrict__ Dvec,
    bf16u* __restrict__ y, float* __restrict__ hf) {
  const int blk = blockIdx.x;
  const int pq = blk & 3;
  const int bh = blk >> 2;
  const int b = bh >> 5, hh = bh & (NHEADS - 1);
  const int lane = threadIdx.x;
  const int pl = lane & 15;
  const int ng = lane >> 4;
  const int p = pq * 16 + pl;

  __shared__ float sB[SCAN_T][64];
  __shared__ float sC[SCAN_T][64];
  __shared__ float sx[SCAN_T][16];
  __shared__ float sdt[SCAN_T];

  float h[16];
#pragma unroll
  for (int j = 0; j < 16; ++j) h[j] = 0.f;

  const float Ah = -expf(A_log[hh]);
  const float Dh = Dvec[hh];
  const size_t base = (size_t)b * SEQLEN * DINNER + hh * HEADDIM;
  const float* xp = xc + base + pq * 16;
  const float* Bp = Bm + base;
  const float* Cp = Cm + base;
  const float* dtp = dtb + (size_t)b * SEQLEN * NHEADS + hh;
  bf16u* yp = y + base + pq * 16;

  const int rowbc = lane >> 4;            // unused helper
  (void)rowbc;
  const int rx_row = lane >> 2, rx_c = (lane & 3) * 4;

  float4 rB[4], rC[4], rx;
  float rdt = 0.f;
  // load batch 0
#pragma unroll
  for (int j = 0; j < 4; ++j) {
    const int slot = j * 64 + lane;
    const int row = slot >> 4, c4 = (slot & 15) * 4;
    rB[j] = *(const float4*)(Bp + (size_t)row * DINNER + c4);
    rC[j] = *(const float4*)(Cp + (size_t)row * DINNER + c4);
  }
  rx = *(const float4*)(xp + (size_t)rx_row * DINNER + rx_c);
  if (lane < 16) rdt = dtp[(size_t)lane * NHEADS];

  for (int t0 = 0; t0 < SEQLEN; t0 += SCAN_T) {
    // regs -> LDS
#pragma unroll
    for (int j = 0; j < 4; ++j) {
      const int slot = j * 64 + lane;
      const int row = slot >> 4, c4 = (slot & 15) * 4;
      *(float4*)&sB[row][c4] = rB[j];
      *(float4*)&sC[row][c4] = rC[j];
    }
    *(float4*)&sx[rx_row][rx_c] = rx;
    if (lane < 16) sdt[lane] = rdt;
    __syncthreads();
    // prefetch next batch
    if (t0 + SCAN_T < SEQLEN) {
      const int l1 = t0 + SCAN_T;
#pragma unroll
      for (int j = 0; j < 4; ++j) {
        const int slot = j * 64 + lane;
        const int row = l1 + (slot >> 4), c4 = (slot & 15) * 4;
        rB[j] = *(const float4*)(Bp + (size_t)row * DINNER + c4);
        rC[j] = *(const float4*)(Cp + (size_t)row * DINNER + c4);
      }
      rx = *(const float4*)(xp + (size_t)(l1 + rx_row) * DINNER + rx_c);
      if (lane < 16) rdt = dtp[(size_t)(l1 + lane) * NHEADS];
    }
    // decay factors for the batch
    float av[SCAN_T];
#pragma unroll
    for (int s = 0; s < SCAN_T; ++s) av[s] = __expf(Ah * sdt[s]);
    // 16 sequential steps
#pragma unroll
    for (int s = 0; s < SCAN_T; ++s) {
      const float dtv = sdt[s];
      const float xv = sx[s][pl];
      const float coef = dtv * xv;
      const float4* Bv4 = (const float4*)&sB[s][ng * 16];
      const float4* Cv4 = (const float4*)&sC[s][ng * 16];
      float yacc = 0.f;
#pragma unroll
      for (int q = 0; q < 4; ++q) {
        const float4 bq = Bv4[q], cq = Cv4[q];
        h[q * 4 + 0] = av[s] * h[q * 4 + 0] + coef * bq.x; yacc += h[q * 4 + 0] * cq.x;
        h[q * 4 + 1] = av[s] * h[q * 4 + 1] + coef * bq.y; yacc += h[q * 4 + 1] * cq.y;
        h[q * 4 + 2] = av[s] * h[q * 4 + 2] + coef * bq.z; yacc += h[q * 4 + 2] * cq.z;
        h[q * 4 + 3] = av[s] * h[q * 4 + 3] + coef * bq.w; yacc += h[q * 4 + 3] * cq.w;
      }
      yacc += __shfl_xor(yacc, 16);
      yacc += __shfl_xor(yacc, 32);
      if (lane < 16) yp[(size_t)(t0 + s) * DINNER + pl] = f2b(yacc + Dh * xv);
    }
    __syncthreads();
  }

  // final state [B,H,P,N]
  float* hq = hf + ((size_t)bh * HEADDIM + p) * DSTATE + ng * 16;
#pragma unroll
  for (int q = 0; q < 4; ++q)
    *(float4*)(hq + q * 4) = make_float4(h[q * 4], h[q * 4 + 1], h[q * 4 + 2], h[q * 4 + 3]);
}

// ---------------------------------------------------------------------------
// LayerNorm(2048) + SiLU(z) gate. bf16 y/z in, bf16 out. One block per token.
// ---------------------------------------------------------------------------
__global__ __launch_bounds__(256) void ln_gate(
    const bf16u* __restrict__ y, const bf16u* __restrict__ xzb,
    const float* __restrict__ lnw, const float* __restrict__ lnb,
    bf16u* __restrict__ out) {
  const int tok = blockIdx.x;
  const int t = threadIdx.x;
  const short8 yv8 = *(const short8*)(y + (size_t)tok * DINNER + t * 8);
  const short8 zv8 = *(const short8*)(xzb + (size_t)tok * (2 * DINNER) + DINNER + t * 8);
  float v[8];
  float s = 0.f, s2 = 0.f;
#pragma unroll
  for (int j = 0; j < 8; ++j) {
    v[j] = b2f(yv8[j]);
    s += v[j];
    s2 += v[j] * v[j];
  }
#pragma unroll
  for (int off = 32; off > 0; off >>= 1) {
    s += __shfl_down(s, off);
    s2 += __shfl_down(s2, off);
  }
  __shared__ float ws[4], ws2[4];
  const int wid = t >> 6;
  if ((t & 63) == 0) { ws[wid] = s; ws2[wid] = s2; }
  __syncthreads();
  const float mean = (ws[0] + ws[1] + ws[2] + ws[3]) * (1.f / DINNER);
  const float m2 = (ws2[0] + ws2[1] + ws2[2] + ws2[3]) * (1.f / DINNER);
  const float rstd = rsqrtf(m2 - mean * mean + 1e-5f);
  const float4 w0 = *(const float4*)(lnw + t * 8);
  const float4 w1 = *(const float4*)(lnw + t * 8 + 4);
  const float4 b0 = *(const float4*)(lnb + t * 8);
  const float4 b1 = *(const float4*)(lnb + t * 8 + 4);
  const float wv[8] = {w0.x, w0.y, w0.z, w0.w, w1.x, w1.y, w1.z, w1.w};
  const float bv[8] = {b0.x, b0.y, b0.z, b0.w, b1.x, b1.y, b1.z, b1.w};
  short8 o;
#pragma unroll
  for (int j = 0; j < 8; ++j) {
    const float zn = b2f(zv8[j]);
    const float gate = zn / (1.f + __expf(-zn));
    o[j] = (short)f2b(((v[j] - mean) * rstd * wv[j] + bv[j]) * gate);
  }
  *(short8*)(out + (size_t)tok * DINNER + t * 8) = o;
}

// ---------------------------------------------------------------------------
extern "C" void kernel_launch(void* const* d_in, const int* in_sizes, int n_in,
                              void* d_out, int out_size, void* d_ws, size_t ws_size,
                              hipStream_t stream) {
  const float* hidden = (const float*)d_in[0];
  const float* in_proj_w = (const float*)d_in[1];
  const float* conv_w = (const float*)d_in[2];
  const float* conv_b = (const float*)d_in[3];
  const float* A_log = (const float*)d_in[4];
  const float* dt_w = (const float*)d_in[5];
  const float* dt_b = (const float*)d_in[6];
  const float* B_w = (const float*)d_in[7];
  const float* C_w = (const float*)d_in[8];
  const float* Dv = (const float*)d_in[9];
  const float* ln_w = (const float*)d_in[10];
  const float* ln_b = (const float*)d_in[11];
  const float* out_proj_w = (const float*)d_in[12];

  float* out = (float*)d_out;
  float* f = (float*)d_ws;
  const size_t M1 = 1u << 20;

  // workspace layout (units: floats); bf16 arrays use 2 elems per slot
  bf16u* xzb   = (bf16u*)(f + 0);          // 8M bf16   [0,4M)
  float* xc    = f + 4 * M1;               //            [4M,8M)
  bf16u* xcb   = (bf16u*)(f + 8 * M1);     // 4M bf16   [8M,10M)
  float* Bm    = f + 10 * M1;              //            [10M,14M)
  float* Cm    = f + 14 * M1;              //            [14M,18M)
  bf16u* yscb  = (bf16u*)(f + 18 * M1);    // 4M bf16   [18M,20M)
  float* dtbuf = f + 20 * M1;              // 64K        [20M,20M+64K)
  bf16u* wBb   = (bf16u*)(f + 20 * M1 + 131072);  // 4M bf16 (2M slots)
  bf16u* wCb   = wBb + 4 * M1;
  bf16u* wOb   = wCb + 4 * M1;             // 2M bf16
  bf16u* wdtb  = wOb + 2 * M1;             // 64K bf16
  // temporally-disjoint aliases:
  bf16u* wInb    = (bf16u*)(f + 18 * M1);  // alias yscb (dead before scan)
  bf16u* hiddenb = (bf16u*)(f + 12 * M1);  // alias Bm[2M..3M) (dead before B-GEMM)
  bf16u* ygb     = (bf16u*)(f + 10 * M1);  // alias Bm (dead after scan)

  float* hf = out + OUT_ELEMS;

  // 0. conversions to bf16
  cvt_bf16<<<1024, 256, 0, stream>>>(hidden, hiddenb, 2 * M1);
  cvt_bf16<<<2048, 256, 0, stream>>>(in_proj_w, wInb, 4 * M1);
  cvt_bf16<<<2048, 256, 0, stream>>>(B_w, wBb, 4 * M1);
  cvt_bf16<<<2048, 256, 0, stream>>>(C_w, wCb, 4 * M1);
  cvt_bf16<<<1024, 256, 0, stream>>>(out_proj_w, wOb, 2 * M1);
  cvt_bf16<<<32, 256, 0, stream>>>(dt_w, wdtb, NHEADS * DINNER);

  // 1. xz = hidden @ in_proj_w^T  [2048 x 4096], K=1024  (bf16 out)
  gemm_mfma<bf16u><<<dim3(32, 16), 256, 0, stream>>>(hiddenb, wInb, xzb,
                                                     NTOK, 2 * DINNER, DMODEL);
  // 2. conv + SiLU
  conv_silu<<<2048, 256, 0, stream>>>(xzb, conv_w, conv_b, xc, xcb);
  // 3. dt_raw = xc @ dt_w^T  [2048 x 32], K=2048 (f32 out)
  gemm_mfma<float><<<dim3(1, 16), 256, 0, stream>>>(xcb, wdtb, dtbuf,
                                                    NTOK, NHEADS, DINNER);
  // 4. B/C projections (f32 out)
  gemm_mfma<float><<<dim3(16, 16), 256, 0, stream>>>(xcb, wBb, Bm,
                                                     NTOK, DINNER, DINNER);
  gemm_mfma<float><<<dim3(16, 16), 256, 0, stream>>>(xcb, wCb, Cm,
                                                     NTOK, DINNER, DINNER);
  // 5. dt = softplus(dt_raw + dt_b)
  dt_act<<<(NTOK * NHEADS) / 256, 256, 0, stream>>>(dtbuf, dt_b);
  // 6. scan -> ysc (bf16), h_final (f32)
  scan_kernel<<<256, 64, 0, stream>>>(xc, dtbuf, Bm, Cm, A_log, Dv, yscb, hf);
  // 7. LN + gate -> ygb (bf16)
  ln_gate<<<NTOK, 256, 0, stream>>>(yscb, xzb, ln_w, ln_b, ygb);
  // 8. out = yg @ out_proj_w^T  [2048 x 1024], K=2048 (f32 out)
  gemm_mfma<float><<<dim3(8, 16), 256, 0, stream>>>(ygb, wOb, out,
                                                    NTOK, DMODEL, DINNER);
}

// Round 3
// 297.645 us; speedup vs baseline: 5.2135x; 1.7106x over previous
//
#include <hip/hip_runtime.h>
#include <math.h>

#define BATCH 2
#define SEQLEN 1024
#define DMODEL 1024
#define DINNER 2048
#define NHEADS 32
#define HEADDIM 64
#define DSTATE 64
#define NTOK (BATCH * SEQLEN)                 // 2048
#define OUT_ELEMS (BATCH * SEQLEN * DMODEL)   // 2097152
#define NCHUNK 16                             // chunks per sequence (Q=64)
#define LDP 72                                // padded LDS stride (bf16 elems)

typedef unsigned short bf16u;
typedef __attribute__((ext_vector_type(8))) short short8;
typedef __attribute__((ext_vector_type(4))) float f32x4;

__device__ __forceinline__ float b2f(short u) {
  return __uint_as_float(((unsigned)(unsigned short)u) << 16);
}
__device__ __forceinline__ unsigned short f2b(float f) {
  unsigned u = __float_as_uint(f);
  u += 0x7fff + ((u >> 16) & 1);   // RNE
  return (unsigned short)(u >> 16);
}

__device__ __forceinline__ void gload16(const void* g, void* l) {
  __builtin_amdgcn_global_load_lds(
      (const __attribute__((address_space(1))) unsigned int*)g,
      (__attribute__((address_space(3))) unsigned int*)l, 16, 0, 0);
}

__device__ __forceinline__ void stv(float* p, float v) { *p = v; }
__device__ __forceinline__ void stv(bf16u* p, float v) { *p = f2b(v); }

// ---------------------------------------------------------------------------
// f32 -> bf16 conversion, 8 elems/thread
// ---------------------------------------------------------------------------
__global__ __launch_bounds__(256) void cvt_bf16(const float* __restrict__ in,
                                                bf16u* __restrict__ out, int n) {
  const int i = (blockIdx.x * 256 + threadIdx.x) * 8;
  if (i >= n) return;
  const float4 a = *(const float4*)(in + i);
  const float4 b = *(const float4*)(in + i + 4);
  short8 o;
  o[0] = f2b(a.x); o[1] = f2b(a.y); o[2] = f2b(a.z); o[3] = f2b(a.w);
  o[4] = f2b(b.x); o[5] = f2b(b.y); o[6] = f2b(b.z); o[7] = f2b(b.w);
  *(short8*)(out + i) = o;
}

// ---------------------------------------------------------------------------
// bf16 MFMA GEMM:  C[m,n] = sum_k A[m][k] * B[n][k]   (A@B^T), f32 accum.
// Tile 128x128, BK=32, 256 threads (4 waves, 2x2 of 64x64).
// ---------------------------------------------------------------------------
template <typename OutT>
__global__ __launch_bounds__(256) void gemm_mfma(
    const bf16u* __restrict__ A, const bf16u* __restrict__ B,
    OutT* __restrict__ C, int M, int N, int K) {
  __shared__ bf16u sA[128 * 32];
  __shared__ bf16u sB[128 * 32];
  const int t = threadIdx.x;
  const int lane = t & 63, wave = t >> 6;
  const int bm = blockIdx.y * 128, bn = blockIdx.x * 128;
  const int wr = wave >> 1, wc = wave & 1;

  const int ra0 = bm + (t >> 2), ra1 = bm + 64 + (t >> 2);
  int rb0 = bn + (t >> 2), rb1 = bn + 64 + (t >> 2);
  rb0 = rb0 < N ? rb0 : N - 1;
  rb1 = rb1 < N ? rb1 : N - 1;
  const int kc = (t & 3) * 8;

  bf16u* ldsA0 = sA + (wave * 64) * 8;
  bf16u* ldsA1 = sA + (256 + wave * 64) * 8;
  bf16u* ldsB0 = sB + (wave * 64) * 8;
  bf16u* ldsB1 = sB + (256 + wave * 64) * 8;

  const f32x4 zero = {0.f, 0.f, 0.f, 0.f};
  f32x4 acc[4][4];
#pragma unroll
  for (int m = 0; m < 4; ++m)
#pragma unroll
    for (int n = 0; n < 4; ++n) acc[m][n] = zero;

  const int ln15 = lane & 15, kq = lane >> 4;

  for (int k0 = 0; k0 < K; k0 += 32) {
    __syncthreads();
    gload16(A + (size_t)ra0 * K + k0 + kc, ldsA0);
    gload16(A + (size_t)ra1 * K + k0 + kc, ldsA1);
    gload16(B + (size_t)rb0 * K + k0 + kc, ldsB0);
    gload16(B + (size_t)rb1 * K + k0 + kc, ldsB1);
    __syncthreads();
    short8 af[4], bfr[4];
#pragma unroll
    for (int m = 0; m < 4; ++m)
      af[m] = *(const short8*)&sA[(wr * 64 + m * 16 + ln15) * 32 + kq * 8];
#pragma unroll
    for (int n = 0; n < 4; ++n)
      bfr[n] = *(const short8*)&sB[(wc * 64 + n * 16 + ln15) * 32 + kq * 8];
#pragma unroll
    for (int m = 0; m < 4; ++m)
#pragma unroll
      for (int n = 0; n < 4; ++n)
        acc[m][n] = __builtin_amdgcn_mfma_f32_16x16x32_bf16(af[m], bfr[n], acc[m][n], 0, 0, 0);
  }

  const int rbase = bm + wr * 64, cbase = bn + wc * 64;
#pragma unroll
  for (int m = 0; m < 4; ++m) {
#pragma unroll
    for (int n = 0; n < 4; ++n) {
      const int col = cbase + n * 16 + ln15;
      if (col < N) {
#pragma unroll
        for (int r = 0; r < 4; ++r) {
          const int row = rbase + m * 16 + kq * 4 + r;
          stv(&C[(size_t)row * N + col], acc[m][n][r]);
        }
      }
    }
  }
}

// ---------------------------------------------------------------------------
// Depthwise causal conv (width 4) + bias + SiLU. bf16 in/out.
// ---------------------------------------------------------------------------
__global__ __launch_bounds__(256) void conv_silu(
    const bf16u* __restrict__ xzb, const float* __restrict__ cw,
    const float* __restrict__ cb, bf16u* __restrict__ xcb) {
  const int i = blockIdx.x * 256 + threadIdx.x;  // 0..512K
  const int c8 = (i & 255) * 8;
  const int tok = i >> 8;
  const int l = tok & (SEQLEN - 1);
  const bf16u* xp = xzb + (size_t)tok * (2 * DINNER) + c8;
  const short8 zer = {0, 0, 0, 0, 0, 0, 0, 0};
  const short8 x0 = *(const short8*)xp;
  const short8 x1 = (l >= 1) ? *(const short8*)(xp - 1 * (2 * DINNER)) : zer;
  const short8 x2 = (l >= 2) ? *(const short8*)(xp - 2 * (2 * DINNER)) : zer;
  const short8 x3 = (l >= 3) ? *(const short8*)(xp - 3 * (2 * DINNER)) : zer;
  short8 ob;
#pragma unroll
  for (int j = 0; j < 8; ++j) {
    const float4 w = *(const float4*)(cw + (c8 + j) * 4);
    float acc = cb[c8 + j] + w.w * b2f(x0[j]);
    acc += w.z * b2f(x1[j]);
    acc += w.y * b2f(x2[j]);
    acc += w.x * b2f(x3[j]);
    const float s = acc / (1.f + __expf(-acc));
    ob[j] = (short)f2b(s);
  }
  *(short8*)(xcb + (size_t)tok * DINNER + c8) = ob;
}

// ---------------------------------------------------------------------------
// dt activation: softplus(dt + dt_b), in-place f32
// ---------------------------------------------------------------------------
__global__ __launch_bounds__(256) void dt_act(float* __restrict__ dtb,
                                              const float* __restrict__ dt_b) {
  const int i = blockIdx.x * 256 + threadIdx.x;
  if (i >= NTOK * NHEADS) return;
  const float v = dtb[i] + dt_b[i & (NHEADS - 1)];
  dtb[i] = (v > 20.f) ? v : log1pf(expf(v));
}

// ---------------------------------------------------------------------------
// Chunked SSD, stage 1 (per chunk): decay cumsum, G=C@B^T masked -> P,
// Y_intra = P@X, S = X^T diag(w) B. One block per (b,h,c); 256 threads.
// ---------------------------------------------------------------------------
__global__ __launch_bounds__(256) void chunk_intra(
    const bf16u* __restrict__ xcb, const bf16u* __restrict__ Bmb,
    const bf16u* __restrict__ Cmb, const float* __restrict__ dtb,
    const float* __restrict__ A_log, float* __restrict__ ybuf,
    float* __restrict__ Sbuf, float* __restrict__ rbuf,
    float* __restrict__ lambuf) {
  __shared__ bf16u sC[64 * LDP], sB[64 * LDP], sXT[64 * LDP];
  __shared__ bf16u sWBT[64 * LDP], sP[64 * LDP];
  __shared__ float sS[64], sDt[64], sW[64];

  const int blk = blockIdx.x;
  const int bh = blk >> 4, c = blk & (NCHUNK - 1);
  const int b = bh >> 5, h = bh & (NHEADS - 1);
  const int t = threadIdx.x, lane = t & 63, wave = t >> 6;
  const int t0 = b * SEQLEN + c * 64;
  const size_t rowbase = (size_t)t0 * DINNER + h * 64;

  // ---- P0: staging + decay scan ----
  if (wave == 0) {
    const float dtv = dtb[(size_t)(t0 + lane) * NHEADS + h];
    const float Ah = -__expf(A_log[h]);
    float s = Ah * dtv;
#pragma unroll
    for (int off = 1; off < 64; off <<= 1) {
      const float o = __shfl_up(s, off);
      if (lane >= off) s += o;
    }
    const float stot = __shfl(s, 63);
    sS[lane] = s;
    sDt[lane] = dtv;
    sW[lane] = __expf(stot - s) * dtv;
    rbuf[(size_t)blk * 64 + lane] = __expf(s);
    if (lane == 0) lambuf[blk] = __expf(stot);
  } else if (wave == 1) {
#pragma unroll
    for (int it = 0; it < 8; ++it) {
      const int slot = it * 64 + lane;
      const int r = slot >> 3, c8 = (slot & 7) * 8;
      *(short8*)&sC[r * LDP + c8] =
          *(const short8*)&Cmb[rowbase + (size_t)r * DINNER + c8];
    }
  } else if (wave == 2) {
#pragma unroll
    for (int it = 0; it < 8; ++it) {
      const int slot = it * 64 + lane;
      const int r = slot >> 3, c8 = (slot & 7) * 8;
      *(short8*)&sB[r * LDP + c8] =
          *(const short8*)&Bmb[rowbase + (size_t)r * DINNER + c8];
    }
  } else {
#pragma unroll
    for (int it = 0; it < 8; ++it) {
      const int slot = it * 64 + lane;
      const int j = slot >> 3, p0 = (slot & 7) * 8;
      const short8 v = *(const short8*)&xcb[rowbase + (size_t)j * DINNER + p0];
#pragma unroll
      for (int k = 0; k < 8; ++k) sXT[(p0 + k) * LDP + j] = v[k];
    }
  }
  __syncthreads();

  // ---- P1: WBT[n][j] = w_j * B[j][n]; G mfma + mask -> P ----
  {
    const int j = t >> 2, n0 = (t & 3) * 16;
    const float wj = sW[j];
#pragma unroll
    for (int k = 0; k < 16; ++k)
      sWBT[(n0 + k) * LDP + j] = f2b(wj * b2f(sB[j * LDP + n0 + k]));
  }
  const int ln15 = lane & 15, kq = lane >> 4;
  const int i0 = wave * 16;
  const f32x4 zero = {0.f, 0.f, 0.f, 0.f};
  {
    f32x4 g[4];
#pragma unroll
    for (int jf = 0; jf < 4; ++jf) g[jf] = zero;
#pragma unroll
    for (int k0 = 0; k0 < 64; k0 += 32) {
      const short8 a = *(const short8*)&sC[(i0 + ln15) * LDP + k0 + kq * 8];
#pragma unroll
      for (int jf = 0; jf < 4; ++jf) {
        const short8 bb = *(const short8*)&sB[(jf * 16 + ln15) * LDP + k0 + kq * 8];
        g[jf] = __builtin_amdgcn_mfma_f32_16x16x32_bf16(a, bb, g[jf], 0, 0, 0);
      }
    }
#pragma unroll
    for (int jf = 0; jf < 4; ++jf) {
      const int j = jf * 16 + ln15;
      const float sj = sS[j], dtj = sDt[j];
#pragma unroll
      for (int r = 0; r < 4; ++r) {
        const int i = i0 + kq * 4 + r;
        const float v = (j <= i) ? g[jf][r] * __expf(sS[i] - sj) * dtj : 0.f;
        sP[i * LDP + j] = f2b(v);
      }
    }
  }
  __syncthreads();

  // ---- P2: Y_intra = P @ XT^T ; S = XT @ WBT^T ----
  f32x4 yi[4], ss[4];
#pragma unroll
  for (int f = 0; f < 4; ++f) { yi[f] = zero; ss[f] = zero; }
#pragma unroll
  for (int k0 = 0; k0 < 64; k0 += 32) {
    const short8 ap = *(const short8*)&sP[(i0 + ln15) * LDP + k0 + kq * 8];
    const short8 ax = *(const short8*)&sXT[(i0 + ln15) * LDP + k0 + kq * 8];
#pragma unroll
    for (int f = 0; f < 4; ++f) {
      const short8 bx = *(const short8*)&sXT[(f * 16 + ln15) * LDP + k0 + kq * 8];
      const short8 bw = *(const short8*)&sWBT[(f * 16 + ln15) * LDP + k0 + kq * 8];
      yi[f] = __builtin_amdgcn_mfma_f32_16x16x32_bf16(ap, bx, yi[f], 0, 0, 0);
      ss[f] = __builtin_amdgcn_mfma_f32_16x16x32_bf16(ax, bw, ss[f], 0, 0, 0);
    }
  }
  float* yb = ybuf + (size_t)blk * 4096;
  float* sb = Sbuf + (size_t)blk * 4096;
#pragma unroll
  for (int f = 0; f < 4; ++f) {
#pragma unroll
    for (int r = 0; r < 4; ++r) {
      const int row = i0 + kq * 4 + r;
      const int col = f * 16 + ln15;
      yb[row * 64 + col] = yi[f][r];
      sb[row * 64 + col] = ss[f][r];
    }
  }
}

// ---------------------------------------------------------------------------
// Chunked SSD, stage 2: inter-chunk state scan (16 steps, scalar decay).
// One block per (b,h); thread owns 16 contiguous state elements [p][n].
// ---------------------------------------------------------------------------
__global__ __launch_bounds__(256) void chunk_scan(
    const float* __restrict__ Sbuf, const float* __restrict__ lambuf,
    bf16u* __restrict__ Hprevb, float* __restrict__ hf) {
  const int bh = blockIdx.x;
  const int t = threadIdx.x;
  const int e0 = t * 16;
  float H[16];
#pragma unroll
  for (int j = 0; j < 16; ++j) H[j] = 0.f;

  float4 cur[4];
  float lam;
  {
    const float4* sp = (const float4*)(Sbuf + (size_t)(bh * NCHUNK) * 4096 + e0);
#pragma unroll
    for (int q = 0; q < 4; ++q) cur[q] = sp[q];
    lam = lambuf[bh * NCHUNK];
  }
  for (int c = 0; c < NCHUNK; ++c) {
    float4 nxt[4];
    float lamn = 0.f;
    if (c < NCHUNK - 1) {
      const float4* sp = (const float4*)(Sbuf + (size_t)(bh * NCHUNK + c + 1) * 4096 + e0);
#pragma unroll
      for (int q = 0; q < 4; ++q) nxt[q] = sp[q];
      lamn = lambuf[bh * NCHUNK + c + 1];
    }
    short8 o0, o1;
#pragma unroll
    for (int j = 0; j < 8; ++j) o0[j] = (short)f2b(H[j]);
#pragma unroll
    for (int j = 0; j < 8; ++j) o1[j] = (short)f2b(H[8 + j]);
    *(short8*)&Hprevb[(size_t)(bh * NCHUNK + c) * 4096 + e0] = o0;
    *(short8*)&Hprevb[(size_t)(bh * NCHUNK + c) * 4096 + e0 + 8] = o1;
#pragma unroll
    for (int q = 0; q < 4; ++q) {
      H[q * 4 + 0] = lam * H[q * 4 + 0] + cur[q].x;
      H[q * 4 + 1] = lam * H[q * 4 + 1] + cur[q].y;
      H[q * 4 + 2] = lam * H[q * 4 + 2] + cur[q].z;
      H[q * 4 + 3] = lam * H[q * 4 + 3] + cur[q].w;
    }
#pragma unroll
    for (int q = 0; q < 4; ++q) cur[q] = nxt[q];
    lam = lamn;
  }
  float* hp = hf + (size_t)bh * 4096 + e0;
#pragma unroll
  for (int q = 0; q < 4; ++q)
    *(float4*)(hp + q * 4) =
        make_float4(H[q * 4], H[q * 4 + 1], H[q * 4 + 2], H[q * 4 + 3]);
}

// ---------------------------------------------------------------------------
// Chunked SSD, stage 3 (per chunk): Y = Y_intra + r_i * C @ Hprev^T + D*x.
// ---------------------------------------------------------------------------
__global__ __launch_bounds__(256) void chunk_inter(
    const bf16u* __restrict__ Cmb, const bf16u* __restrict__ Hprevb,
    const bf16u* __restrict__ xcb, const float* __restrict__ ybuf,
    const float* __restrict__ rbuf, const float* __restrict__ Dvec,
    bf16u* __restrict__ yout) {
  __shared__ bf16u sC[64 * LDP], sH[64 * LDP];
  __shared__ float sR[64];
  const int blk = blockIdx.x;
  const int bh = blk >> 4, c = blk & (NCHUNK - 1);
  const int b = bh >> 5, h = bh & (NHEADS - 1);
  const int t = threadIdx.x, lane = t & 63, wave = t >> 6;
  const int t0 = b * SEQLEN + c * 64;
  const size_t rowbase = (size_t)t0 * DINNER + h * 64;

#pragma unroll
  for (int it = 0; it < 2; ++it) {
    const int slot = it * 256 + t;          // 0..511
    const int r = slot >> 3, c8 = (slot & 7) * 8;
    *(short8*)&sC[r * LDP + c8] =
        *(const short8*)&Cmb[rowbase + (size_t)r * DINNER + c8];
    *(short8*)&sH[r * LDP + c8] =
        *(const short8*)&Hprevb[(size_t)blk * 4096 + slot * 8];
  }
  if (t < 64) sR[t] = rbuf[(size_t)blk * 64 + t];
  __syncthreads();

  const int ln15 = lane & 15, kq = lane >> 4;
  const int i0 = wave * 16;
  const f32x4 zero = {0.f, 0.f, 0.f, 0.f};
  f32x4 acc[4];
#pragma unroll
  for (int f = 0; f < 4; ++f) acc[f] = zero;
#pragma unroll
  for (int k0 = 0; k0 < 64; k0 += 32) {
    const short8 a = *(const short8*)&sC[(i0 + ln15) * LDP + k0 + kq * 8];
#pragma unroll
    for (int f = 0; f < 4; ++f) {
      const short8 bh8 = *(const short8*)&sH[(f * 16 + ln15) * LDP + k0 + kq * 8];
      acc[f] = __builtin_amdgcn_mfma_f32_16x16x32_bf16(a, bh8, acc[f], 0, 0, 0);
    }
  }
  const float Dh = Dvec[h];
  const float* yb = ybuf + (size_t)blk * 4096;
#pragma unroll
  for (int f = 0; f < 4; ++f) {
    const int p = f * 16 + ln15;
#pragma unroll
    for (int r = 0; r < 4; ++r) {
      const int i = i0 + kq * 4 + r;
      const float xv = b2f((short)xcb[rowbase + (size_t)i * DINNER + p]);
      const float y = yb[i * 64 + p] + sR[i] * acc[f][r] + Dh * xv;
      yout[rowbase + (size_t)i * DINNER + p] = f2b(y);
    }
  }
}

// ---------------------------------------------------------------------------
// LayerNorm(2048) + SiLU(z) gate. bf16 y/z in, bf16 out. One block per token.
// ---------------------------------------------------------------------------
__global__ __launch_bounds__(256) void ln_gate(
    const bf16u* __restrict__ y, const bf16u* __restrict__ xzb,
    const float* __restrict__ lnw, const float* __restrict__ lnb,
    bf16u* __restrict__ out) {
  const int tok = blockIdx.x;
  const int t = threadIdx.x;
  const short8 yv8 = *(const short8*)(y + (size_t)tok * DINNER + t * 8);
  const short8 zv8 = *(const short8*)(xzb + (size_t)tok * (2 * DINNER) + DINNER + t * 8);
  float v[8];
  float s = 0.f, s2 = 0.f;
#pragma unroll
  for (int j = 0; j < 8; ++j) {
    v[j] = b2f(yv8[j]);
    s += v[j];
    s2 += v[j] * v[j];
  }
#pragma unroll
  for (int off = 32; off > 0; off >>= 1) {
    s += __shfl_down(s, off);
    s2 += __shfl_down(s2, off);
  }
  __shared__ float ws[4], ws2[4];
  const int wid = t >> 6;
  if ((t & 63) == 0) { ws[wid] = s; ws2[wid] = s2; }
  __syncthreads();
  const float mean = (ws[0] + ws[1] + ws[2] + ws[3]) * (1.f / DINNER);
  const float m2 = (ws2[0] + ws2[1] + ws2[2] + ws2[3]) * (1.f / DINNER);
  const float rstd = rsqrtf(m2 - mean * mean + 1e-5f);
  const float4 w0 = *(const float4*)(lnw + t * 8);
  const float4 w1 = *(const float4*)(lnw + t * 8 + 4);
  const float4 b0 = *(const float4*)(lnb + t * 8);
  const float4 b1 = *(const float4*)(lnb + t * 8 + 4);
  const float wv[8] = {w0.x, w0.y, w0.z, w0.w, w1.x, w1.y, w1.z, w1.w};
  const float bv[8] = {b0.x, b0.y, b0.z, b0.w, b1.x, b1.y, b1.z, b1.w};
  short8 o;
#pragma unroll
  for (int j = 0; j < 8; ++j) {
    const float zn = b2f(zv8[j]);
    const float gate = zn / (1.f + __expf(-zn));
    o[j] = (short)f2b(((v[j] - mean) * rstd * wv[j] + bv[j]) * gate);
  }
  *(short8*)(out + (size_t)tok * DINNER + t * 8) = o;
}

// ---------------------------------------------------------------------------
extern "C" void kernel_launch(void* const* d_in, const int* in_sizes, int n_in,
                              void* d_out, int out_size, void* d_ws, size_t ws_size,
                              hipStream_t stream) {
  const float* hidden = (const float*)d_in[0];
  const float* in_proj_w = (const float*)d_in[1];
  const float* conv_w = (const float*)d_in[2];
  const float* conv_b = (const float*)d_in[3];
  const float* A_log = (const float*)d_in[4];
  const float* dt_w = (const float*)d_in[5];
  const float* dt_b = (const float*)d_in[6];
  const float* B_w = (const float*)d_in[7];
  const float* C_w = (const float*)d_in[8];
  const float* Dv = (const float*)d_in[9];
  const float* ln_w = (const float*)d_in[10];
  const float* ln_b = (const float*)d_in[11];
  const float* out_proj_w = (const float*)d_in[12];

  float* out = (float*)d_out;
  float* f = (float*)d_ws;
  const size_t M1 = 1u << 20;

  // workspace layout (float units):
  bf16u* xzb    = (bf16u*)(f + 0);            // [0,4M)
  bf16u* xcb    = (bf16u*)(f + 4 * M1);       // [4M,6M)
  bf16u* Bmb    = (bf16u*)(f + 6 * M1);       // [6M,8M)
  bf16u* Cmb    = (bf16u*)(f + 8 * M1);       // [8M,10M)
  float* dtbuf  = f + 10 * M1;                // [10M,10M+64K)
  float* rbuf   = f + 10 * M1 + 65536;        // [.., +64K)
  float* lambuf = f + 10 * M1 + 131072;       // [.., +1K)
  float* ybuf   = f + 11 * M1;                // [11M,15M)
  float* Sbuf   = f + 15 * M1;                // [15M,19M)
  bf16u* Hprevb = (bf16u*)(f + 19 * M1);      // [19M,21M)
  bf16u* wOb    = (bf16u*)(f + 21 * M1);      // [21M,22M)
  bf16u* wdtb   = (bf16u*)(f + 22 * M1);      // [22M,22M+32K)
  // temporally-disjoint aliases:
  bf16u* wBb     = (bf16u*)(f + 11 * M1);     // alias ybuf (dead before chunk_intra)
  bf16u* wCb     = (bf16u*)(f + 13 * M1);     // alias ybuf
  bf16u* wInb    = (bf16u*)(f + 15 * M1);     // alias Sbuf (dead before chunk_intra)
  bf16u* hiddenb = (bf16u*)(f + 19 * M1);     // alias Hprevb (dead before chunk_scan)
  bf16u* yscb    = (bf16u*)(f + 15 * M1);     // alias Sbuf (dead after chunk_scan)
  bf16u* ygb     = (bf16u*)(f + 6 * M1);      // alias Bmb (dead after chunk_intra)

  float* hf = out + OUT_ELEMS;

  // 0. conversions to bf16
  cvt_bf16<<<1024, 256, 0, stream>>>(hidden, hiddenb, 2 * M1);
  cvt_bf16<<<2048, 256, 0, stream>>>(in_proj_w, wInb, 4 * M1);
  cvt_bf16<<<2048, 256, 0, stream>>>(B_w, wBb, 4 * M1);
  cvt_bf16<<<2048, 256, 0, stream>>>(C_w, wCb, 4 * M1);
  cvt_bf16<<<1024, 256, 0, stream>>>(out_proj_w, wOb, 2 * M1);
  cvt_bf16<<<32, 256, 0, stream>>>(dt_w, wdtb, NHEADS * DINNER);

  // 1. xz = hidden @ in_proj_w^T  [2048 x 4096], K=1024  (bf16 out)
  gemm_mfma<bf16u><<<dim3(32, 16), 256, 0, stream>>>(hiddenb, wInb, xzb,
                                                     NTOK, 2 * DINNER, DMODEL);
  // 2. conv + SiLU -> xcb (bf16)
  conv_silu<<<2048, 256, 0, stream>>>(xzb, conv_w, conv_b, xcb);
  // 3. dt_raw = xc @ dt_w^T  [2048 x 32], K=2048 (f32 out)
  gemm_mfma<float><<<dim3(1, 16), 256, 0, stream>>>(xcb, wdtb, dtbuf,
                                                    NTOK, NHEADS, DINNER);
  // 4. B/C projections (bf16 out)
  gemm_mfma<bf16u><<<dim3(16, 16), 256, 0, stream>>>(xcb, wBb, Bmb,
                                                     NTOK, DINNER, DINNER);
  gemm_mfma<bf16u><<<dim3(16, 16), 256, 0, stream>>>(xcb, wCb, Cmb,
                                                     NTOK, DINNER, DINNER);
  // 5. dt = softplus(dt_raw + dt_b)
  dt_act<<<(NTOK * NHEADS) / 256, 256, 0, stream>>>(dtbuf, dt_b);
  // 6a. per-chunk intra + states
  chunk_intra<<<BATCH * NHEADS * NCHUNK, 256, 0, stream>>>(
      xcb, Bmb, Cmb, dtbuf, A_log, ybuf, Sbuf, rbuf, lambuf);
  // 6b. inter-chunk scan (also writes h_final)
  chunk_scan<<<BATCH * NHEADS, 256, 0, stream>>>(Sbuf, lambuf, Hprevb, hf);
  // 6c. combine -> y (bf16)
  chunk_inter<<<BATCH * NHEADS * NCHUNK, 256, 0, stream>>>(
      Cmb, Hprevb, xcb, ybuf, rbuf, Dv, yscb);
  // 7. LN + gate -> ygb (bf16)
  ln_gate<<<NTOK, 256, 0, stream>>>(yscb, xzb, ln_w, ln_b, ygb);
  // 8. out = yg @ out_proj_w^T  [2048 x 1024], K=2048 (f32 out)
  gemm_mfma<float><<<dim3(8, 16), 256, 0, stream>>>(ygb, wOb, out,
                                                    NTOK, DMODEL, DINNER);
}

// Round 5
// 229.693 us; speedup vs baseline: 6.7559x; 1.2958x over previous
//
#include <hip/hip_runtime.h>
#include <math.h>

#define BATCH 2
#define SEQLEN 1024
#define DMODEL 1024
#define DINNER 2048
#define NHEADS 32
#define HEADDIM 64
#define DSTATE 64
#define NTOK (BATCH * SEQLEN)                 // 2048
#define OUT_ELEMS (BATCH * SEQLEN * DMODEL)   // 2097152
#define NCHUNK 16                             // chunks per sequence (Q=64)
#define LDP 72                                // padded LDS stride (bf16 elems)

typedef unsigned short bf16u;
typedef __attribute__((ext_vector_type(8))) short short8;
typedef __attribute__((ext_vector_type(4))) float f32x4;

__device__ __forceinline__ float b2f(short u) {
  return __uint_as_float(((unsigned)(unsigned short)u) << 16);
}
__device__ __forceinline__ unsigned short f2b(float f) {
  unsigned u = __float_as_uint(f);
  u += 0x7fff + ((u >> 16) & 1);   // RNE
  return (unsigned short)(u >> 16);
}

__device__ __forceinline__ void gload16(const void* g, void* l) {
  __builtin_amdgcn_global_load_lds(
      (const __attribute__((address_space(1))) unsigned int*)g,
      (__attribute__((address_space(3))) unsigned int*)l, 16, 0, 0);
}

__device__ __forceinline__ void stv(float* p, float v) { *p = v; }
__device__ __forceinline__ void stv(bf16u* p, float v) { *p = f2b(v); }

// ---------------------------------------------------------------------------
// f32 -> bf16 conversion, 8 elems/thread
// ---------------------------------------------------------------------------
__global__ __launch_bounds__(256) void cvt_bf16(const float* __restrict__ in,
                                                bf16u* __restrict__ out, int n) {
  const int i = (blockIdx.x * 256 + threadIdx.x) * 8;
  if (i >= n) return;
  const float4 a = *(const float4*)(in + i);
  const float4 b = *(const float4*)(in + i + 4);
  short8 o;
  o[0] = f2b(a.x); o[1] = f2b(a.y); o[2] = f2b(a.z); o[3] = f2b(a.w);
  o[4] = f2b(b.x); o[5] = f2b(b.y); o[6] = f2b(b.z); o[7] = f2b(b.w);
  *(short8*)(out + i) = o;
}

// ---------------------------------------------------------------------------
// bf16 MFMA GEMM:  C[m,n] = sum_k A[m][k+kbase] * B[n][k+kbase], f32 accum.
// Tile 128x128, BK=32, 256 threads (4 waves, 2x2 of 64x64).
// Triple-buffered LDS, prefetch distance 2, counted vmcnt (never 0 mid-loop).
// grid.z = split-K slices; slice z handles k in [z*Ksub, (z+1)*Ksub),
// writes to C + z*zstrideC.  lda/ldb are row strides of A/B.
// ---------------------------------------------------------------------------
template <typename OutT>
__global__ __launch_bounds__(256) void gemm_mfma(
    const bf16u* __restrict__ A, const bf16u* __restrict__ B,
    OutT* __restrict__ C, int M, int N, int Ksub, int lda, int ldb,
    size_t zstrideC) {
  __shared__ bf16u sA[3][128 * 32];
  __shared__ bf16u sB[3][128 * 32];
  const int t = threadIdx.x;
  const int lane = t & 63, wave = t >> 6;
  const int bm = blockIdx.y * 128, bn = blockIdx.x * 128;
  const int wr = wave >> 1, wc = wave & 1;
  const int kbase = blockIdx.z * Ksub;
  OutT* Cz = C + (size_t)blockIdx.z * zstrideC;

  const int ra0 = bm + (t >> 2), ra1 = bm + 64 + (t >> 2);
  int rb0 = bn + (t >> 2), rb1 = bn + 64 + (t >> 2);
  rb0 = rb0 < N ? rb0 : N - 1;
  rb1 = rb1 < N ? rb1 : N - 1;
  const int kc = (t & 3) * 8;

  const bf16u* Ap0 = A + (size_t)ra0 * lda + kbase + kc;
  const bf16u* Ap1 = A + (size_t)ra1 * lda + kbase + kc;
  const bf16u* Bp0 = B + (size_t)rb0 * ldb + kbase + kc;
  const bf16u* Bp1 = B + (size_t)rb1 * ldb + kbase + kc;
  const int ldsoff = (wave * 64) * 8;

#define STAGE(buf, k0)                                   \
  do {                                                   \
    gload16(Ap0 + (k0), sA[buf] + ldsoff);               \
    gload16(Ap1 + (k0), sA[buf] + 2048 + ldsoff);        \
    gload16(Bp0 + (k0), sB[buf] + ldsoff);               \
    gload16(Bp1 + (k0), sB[buf] + 2048 + ldsoff);        \
  } while (0)

  const f32x4 zero = {0.f, 0.f, 0.f, 0.f};
  f32x4 acc[4][4];
#pragma unroll
  for (int m = 0; m < 4; ++m)
#pragma unroll
    for (int n = 0; n < 4; ++n) acc[m][n] = zero;

  const int ln15 = lane & 15, kq = lane >> 4;
  const int nt = Ksub >> 5;

  STAGE(0, 0);
  STAGE(1, 32);
  int curb = 0;
  for (int it = 0; it < nt; ++it) {
    if (it + 2 < nt) {
      const int nb = (it + 2) % 3;
      STAGE(nb, (it + 2) * 32);
      asm volatile("s_waitcnt vmcnt(8)" ::: "memory");
    } else if (it + 1 < nt) {
      asm volatile("s_waitcnt vmcnt(4)" ::: "memory");
    } else {
      asm volatile("s_waitcnt vmcnt(0)" ::: "memory");
    }
    __builtin_amdgcn_s_barrier();
    const bf16u* pA = sA[curb];
    const bf16u* pB = sB[curb];
    short8 af[4], bfr[4];
#pragma unroll
    for (int m = 0; m < 4; ++m)
      af[m] = *(const short8*)&pA[(wr * 64 + m * 16 + ln15) * 32 + kq * 8];
#pragma unroll
    for (int n = 0; n < 4; ++n)
      bfr[n] = *(const short8*)&pB[(wc * 64 + n * 16 + ln15) * 32 + kq * 8];
#pragma unroll
    for (int m = 0; m < 4; ++m)
#pragma unroll
      for (int n = 0; n < 4; ++n)
        acc[m][n] = __builtin_amdgcn_mfma_f32_16x16x32_bf16(af[m], bfr[n], acc[m][n], 0, 0, 0);
    asm volatile("s_waitcnt lgkmcnt(0)" ::: "memory");
    __builtin_amdgcn_s_barrier();
    curb = (curb == 2) ? 0 : curb + 1;
  }
#undef STAGE

  const int rbase = bm + wr * 64, cbase = bn + wc * 64;
#pragma unroll
  for (int m = 0; m < 4; ++m) {
#pragma unroll
    for (int n = 0; n < 4; ++n) {
      const int col = cbase + n * 16 + ln15;
      if (col < N) {
#pragma unroll
        for (int r = 0; r < 4; ++r) {
          const int row = rbase + m * 16 + kq * 4 + r;
          stv(&Cz[(size_t)row * N + col], acc[m][n][r]);
        }
      }
    }
  }
}

// ---------------------------------------------------------------------------
// out = a + b (f32), 4 elems/thread
// ---------------------------------------------------------------------------
__global__ __launch_bounds__(256) void add_f32(const float* __restrict__ a,
                                               const float* __restrict__ b,
                                               float* __restrict__ o, int n) {
  const int i = (blockIdx.x * 256 + threadIdx.x) * 4;
  if (i >= n) return;
  const float4 x = *(const float4*)(a + i);
  const float4 y = *(const float4*)(b + i);
  *(float4*)(o + i) = make_float4(x.x + y.x, x.y + y.y, x.z + y.z, x.w + y.w);
}

// ---------------------------------------------------------------------------
// Depthwise causal conv (width 4) + bias + SiLU. bf16 in/out.
// ---------------------------------------------------------------------------
__global__ __launch_bounds__(256) void conv_silu(
    const bf16u* __restrict__ xzb, const float* __restrict__ cw,
    const float* __restrict__ cb, bf16u* __restrict__ xcb) {
  const int i = blockIdx.x * 256 + threadIdx.x;  // 0..512K
  const int c8 = (i & 255) * 8;
  const int tok = i >> 8;
  const int l = tok & (SEQLEN - 1);
  const bf16u* xp = xzb + (size_t)tok * (2 * DINNER) + c8;
  const short8 zer = {0, 0, 0, 0, 0, 0, 0, 0};
  const short8 x0 = *(const short8*)xp;
  const short8 x1 = (l >= 1) ? *(const short8*)(xp - 1 * (2 * DINNER)) : zer;
  const short8 x2 = (l >= 2) ? *(const short8*)(xp - 2 * (2 * DINNER)) : zer;
  const short8 x3 = (l >= 3) ? *(const short8*)(xp - 3 * (2 * DINNER)) : zer;
  short8 ob;
#pragma unroll
  for (int j = 0; j < 8; ++j) {
    const float4 w = *(const float4*)(cw + (c8 + j) * 4);
    float acc = cb[c8 + j] + w.w * b2f(x0[j]);
    acc += w.z * b2f(x1[j]);
    acc += w.y * b2f(x2[j]);
    acc += w.x * b2f(x3[j]);
    const float s = acc / (1.f + __expf(-acc));
    ob[j] = (short)f2b(s);
  }
  *(short8*)(xcb + (size_t)tok * DINNER + c8) = ob;
}

// ---------------------------------------------------------------------------
// dt activation: softplus(dt + dt_b), in-place f32
// ---------------------------------------------------------------------------
__global__ __launch_bounds__(256) void dt_act(float* __restrict__ dtb,
                                              const float* __restrict__ dt_b) {
  const int i = blockIdx.x * 256 + threadIdx.x;
  if (i >= NTOK * NHEADS) return;
  const float v = dtb[i] + dt_b[i & (NHEADS - 1)];
  dtb[i] = (v > 20.f) ? v : log1pf(expf(v));
}

// ---------------------------------------------------------------------------
// Chunked SSD, stage 1 (per chunk): decay cumsum, G=C@B^T masked -> P,
// Y_intra = P@X (bf16 out), S = X^T diag(w) B. One block per (b,h,c).
// B/C come fused in BCb [NTOK, 4096]: cols [0,2048)=B, [2048,4096)=C.
// ---------------------------------------------------------------------------
__global__ __launch_bounds__(256) void chunk_intra(
    const bf16u* __restrict__ xcb, const bf16u* __restrict__ BCb,
    const float* __restrict__ dtb, const float* __restrict__ A_log,
    bf16u* __restrict__ ybb, float* __restrict__ Sbuf,
    float* __restrict__ rbuf, float* __restrict__ lambuf) {
  __shared__ bf16u sC[64 * LDP], sB[64 * LDP], sXT[64 * LDP];
  __shared__ bf16u sWBT[64 * LDP], sP[64 * LDP];
  __shared__ float sS[64], sDt[64], sW[64];

  const int blk = blockIdx.x;
  const int bh = blk >> 4, c = blk & (NCHUNK - 1);
  const int b = bh >> 5, h = bh & (NHEADS - 1);
  const int t = threadIdx.x, lane = t & 63, wave = t >> 6;
  const int t0 = b * SEQLEN + c * 64;
  const size_t rowbase = (size_t)t0 * DINNER + h * 64;        // x
  const size_t rowBC = (size_t)t0 * 4096 + h * 64;            // fused B/C

  // ---- P0: staging + decay scan ----
  if (wave == 0) {
    const float dtv = dtb[(size_t)(t0 + lane) * NHEADS + h];
    const float Ah = -__expf(A_log[h]);
    float s = Ah * dtv;
#pragma unroll
    for (int off = 1; off < 64; off <<= 1) {
      const float o = __shfl_up(s, off);
      if (lane >= off) s += o;
    }
    const float stot = __shfl(s, 63);
    sS[lane] = s;
    sDt[lane] = dtv;
    sW[lane] = __expf(stot - s) * dtv;
    rbuf[(size_t)blk * 64 + lane] = __expf(s);
    if (lane == 0) lambuf[blk] = __expf(stot);
  } else if (wave == 1) {
#pragma unroll
    for (int it = 0; it < 8; ++it) {
      const int slot = it * 64 + lane;
      const int r = slot >> 3, c8 = (slot & 7) * 8;
      *(short8*)&sC[r * LDP + c8] =
          *(const short8*)&BCb[rowBC + 2048 + (size_t)r * 4096 + c8];
    }
  } else if (wave == 2) {
#pragma unroll
    for (int it = 0; it < 8; ++it) {
      const int slot = it * 64 + lane;
      const int r = slot >> 3, c8 = (slot & 7) * 8;
      *(short8*)&sB[r * LDP + c8] =
          *(const short8*)&BCb[rowBC + (size_t)r * 4096 + c8];
    }
  } else {
#pragma unroll
    for (int it = 0; it < 8; ++it) {
      const int slot = it * 64 + lane;
      const int j = slot >> 3, p0 = (slot & 7) * 8;
      const short8 v = *(const short8*)&xcb[rowbase + (size_t)j * DINNER + p0];
#pragma unroll
      for (int k = 0; k < 8; ++k) sXT[(p0 + k) * LDP + j] = v[k];
    }
  }
  __syncthreads();

  // ---- P1: WBT[n][j] = w_j * B[j][n]; G mfma + mask -> P ----
  {
    const int j = t >> 2, n0 = (t & 3) * 16;
    const float wj = sW[j];
#pragma unroll
    for (int k = 0; k < 16; ++k)
      sWBT[(n0 + k) * LDP + j] = f2b(wj * b2f(sB[j * LDP + n0 + k]));
  }
  const int ln15 = lane & 15, kq = lane >> 4;
  const int i0 = wave * 16;
  const f32x4 zero = {0.f, 0.f, 0.f, 0.f};
  {
    f32x4 g[4];
#pragma unroll
    for (int jf = 0; jf < 4; ++jf) g[jf] = zero;
#pragma unroll
    for (int k0 = 0; k0 < 64; k0 += 32) {
      const short8 a = *(const short8*)&sC[(i0 + ln15) * LDP + k0 + kq * 8];
#pragma unroll
      for (int jf = 0; jf < 4; ++jf) {
        const short8 bb = *(const short8*)&sB[(jf * 16 + ln15) * LDP + k0 + kq * 8];
        g[jf] = __builtin_amdgcn_mfma_f32_16x16x32_bf16(a, bb, g[jf], 0, 0, 0);
      }
    }
#pragma unroll
    for (int jf = 0; jf < 4; ++jf) {
      const int j = jf * 16 + ln15;
      const float sj = sS[j], dtj = sDt[j];
#pragma unroll
      for (int r = 0; r < 4; ++r) {
        const int i = i0 + kq * 4 + r;
        const float v = (j <= i) ? g[jf][r] * __expf(sS[i] - sj) * dtj : 0.f;
        sP[i * LDP + j] = f2b(v);
      }
    }
  }
  __syncthreads();

  // ---- P2: Y_intra = P @ XT^T ; S = XT @ WBT^T ----
  f32x4 yi[4], ss[4];
#pragma unroll
  for (int f = 0; f < 4; ++f) { yi[f] = zero; ss[f] = zero; }
#pragma unroll
  for (int k0 = 0; k0 < 64; k0 += 32) {
    const short8 ap = *(const short8*)&sP[(i0 + ln15) * LDP + k0 + kq * 8];
    const short8 ax = *(const short8*)&sXT[(i0 + ln15) * LDP + k0 + kq * 8];
#pragma unroll
    for (int f = 0; f < 4; ++f) {
      const short8 bx = *(const short8*)&sXT[(f * 16 + ln15) * LDP + k0 + kq * 8];
      const short8 bw = *(const short8*)&sWBT[(f * 16 + ln15) * LDP + k0 + kq * 8];
      yi[f] = __builtin_amdgcn_mfma_f32_16x16x32_bf16(ap, bx, yi[f], 0, 0, 0);
      ss[f] = __builtin_amdgcn_mfma_f32_16x16x32_bf16(ax, bw, ss[f], 0, 0, 0);
    }
  }
  bf16u* yb = ybb + (size_t)blk * 4096;
  float* sb = Sbuf + (size_t)blk * 4096;
#pragma unroll
  for (int f = 0; f < 4; ++f) {
#pragma unroll
    for (int r = 0; r < 4; ++r) {
      const int row = i0 + kq * 4 + r;
      const int col = f * 16 + ln15;
      yb[row * 64 + col] = f2b(yi[f][r]);
      sb[row * 64 + col] = ss[f][r];
    }
  }
}

// ---------------------------------------------------------------------------
// Chunked SSD, stage 2: inter-chunk state scan (16 steps, scalar decay).
// ---------------------------------------------------------------------------
__global__ __launch_bounds__(256) void chunk_scan(
    const float* __restrict__ Sbuf, const float* __restrict__ lambuf,
    bf16u* __restrict__ Hprevb, float* __restrict__ hf) {
  const int bh = blockIdx.x;
  const int t = threadIdx.x;
  const int e0 = t * 16;
  float H[16];
#pragma unroll
  for (int j = 0; j < 16; ++j) H[j] = 0.f;

  float4 cur[4];
  float lam;
  {
    const float4* sp = (const float4*)(Sbuf + (size_t)(bh * NCHUNK) * 4096 + e0);
#pragma unroll
    for (int q = 0; q < 4; ++q) cur[q] = sp[q];
    lam = lambuf[bh * NCHUNK];
  }
  for (int c = 0; c < NCHUNK; ++c) {
    float4 nxt[4];
    float lamn = 0.f;
    if (c < NCHUNK - 1) {
      const float4* sp = (const float4*)(Sbuf + (size_t)(bh * NCHUNK + c + 1) * 4096 + e0);
#pragma unroll
      for (int q = 0; q < 4; ++q) nxt[q] = sp[q];
      lamn = lambuf[bh * NCHUNK + c + 1];
    }
    short8 o0, o1;
#pragma unroll
    for (int j = 0; j < 8; ++j) o0[j] = (short)f2b(H[j]);
#pragma unroll
    for (int j = 0; j < 8; ++j) o1[j] = (short)f2b(H[8 + j]);
    *(short8*)&Hprevb[(size_t)(bh * NCHUNK + c) * 4096 + e0] = o0;
    *(short8*)&Hprevb[(size_t)(bh * NCHUNK + c) * 4096 + e0 + 8] = o1;
#pragma unroll
    for (int q = 0; q < 4; ++q) {
      H[q * 4 + 0] = lam * H[q * 4 + 0] + cur[q].x;
      H[q * 4 + 1] = lam * H[q * 4 + 1] + cur[q].y;
      H[q * 4 + 2] = lam * H[q * 4 + 2] + cur[q].z;
      H[q * 4 + 3] = lam * H[q * 4 + 3] + cur[q].w;
    }
#pragma unroll
    for (int q = 0; q < 4; ++q) cur[q] = nxt[q];
    lam = lamn;
  }
  float* hp = hf + (size_t)bh * 4096 + e0;
#pragma unroll
  for (int q = 0; q < 4; ++q)
    *(float4*)(hp + q * 4) =
        make_float4(H[q * 4], H[q * 4 + 1], H[q * 4 + 2], H[q * 4 + 3]);
}

// ---------------------------------------------------------------------------
// Chunked SSD, stage 3 (per chunk): Y = Y_intra + r_i * C @ Hprev^T + D*x.
// ---------------------------------------------------------------------------
__global__ __launch_bounds__(256) void chunk_inter(
    const bf16u* __restrict__ BCb, const bf16u* __restrict__ Hprevb,
    const bf16u* __restrict__ xcb, const bf16u* __restrict__ ybb,
    const float* __restrict__ rbuf, const float* __restrict__ Dvec,
    bf16u* __restrict__ yout) {
  __shared__ bf16u sC[64 * LDP], sH[64 * LDP];
  __shared__ float sR[64];
  const int blk = blockIdx.x;
  const int bh = blk >> 4, c = blk & (NCHUNK - 1);
  const int b = bh >> 5, h = bh & (NHEADS - 1);
  const int t = threadIdx.x, lane = t & 63, wave = t >> 6;
  const int t0 = b * SEQLEN + c * 64;
  const size_t rowbase = (size_t)t0 * DINNER + h * 64;
  const size_t rowBC = (size_t)t0 * 4096 + h * 64;

#pragma unroll
  for (int it = 0; it < 2; ++it) {
    const int slot = it * 256 + t;          // 0..511
    const int r = slot >> 3, c8 = (slot & 7) * 8;
    *(short8*)&sC[r * LDP + c8] =
        *(const short8*)&BCb[rowBC + 2048 + (size_t)r * 4096 + c8];
    *(short8*)&sH[r * LDP + c8] =
        *(const short8*)&Hprevb[(size_t)blk * 4096 + slot * 8];
  }
  if (t < 64) sR[t] = rbuf[(size_t)blk * 64 + t];
  __syncthreads();

  const int ln15 = lane & 15, kq = lane >> 4;
  const int i0 = wave * 16;
  const f32x4 zero = {0.f, 0.f, 0.f, 0.f};
  f32x4 acc[4];
#pragma unroll
  for (int f = 0; f < 4; ++f) acc[f] = zero;
#pragma unroll
  for (int k0 = 0; k0 < 64; k0 += 32) {
    const short8 a = *(const short8*)&sC[(i0 + ln15) * LDP + k0 + kq * 8];
#pragma unroll
    for (int f = 0; f < 4; ++f) {
      const short8 bh8 = *(const short8*)&sH[(f * 16 + ln15) * LDP + k0 + kq * 8];
      acc[f] = __builtin_amdgcn_mfma_f32_16x16x32_bf16(a, bh8, acc[f], 0, 0, 0);
    }
  }
  const float Dh = Dvec[h];
  const bf16u* yb = ybb + (size_t)blk * 4096;
#pragma unroll
  for (int f = 0; f < 4; ++f) {
    const int p = f * 16 + ln15;
#pragma unroll
    for (int r = 0; r < 4; ++r) {
      const int i = i0 + kq * 4 + r;
      const float xv = b2f((short)xcb[rowbase + (size_t)i * DINNER + p]);
      const float y = b2f((short)yb[i * 64 + p]) + sR[i] * acc[f][r] + Dh * xv;
      yout[rowbase + (size_t)i * DINNER + p] = f2b(y);
    }
  }
}

// ---------------------------------------------------------------------------
// LayerNorm(2048) + SiLU(z) gate. bf16 y/z in, bf16 out. One block per token.
// ---------------------------------------------------------------------------
__global__ __launch_bounds__(256) void ln_gate(
    const bf16u* __restrict__ y, const bf16u* __restrict__ xzb,
    const float* __restrict__ lnw, const float* __restrict__ lnb,
    bf16u* __restrict__ out) {
  const int tok = blockIdx.x;
  const int t = threadIdx.x;
  const short8 yv8 = *(const short8*)(y + (size_t)tok * DINNER + t * 8);
  const short8 zv8 = *(const short8*)(xzb + (size_t)tok * (2 * DINNER) + DINNER + t * 8);
  float v[8];
  float s = 0.f, s2 = 0.f;
#pragma unroll
  for (int j = 0; j < 8; ++j) {
    v[j] = b2f(yv8[j]);
    s += v[j];
    s2 += v[j] * v[j];
  }
#pragma unroll
  for (int off = 32; off > 0; off >>= 1) {
    s += __shfl_down(s, off);
    s2 += __shfl_down(s2, off);
  }
  __shared__ float ws[4], ws2[4];
  const int wid = t >> 6;
  if ((t & 63) == 0) { ws[wid] = s; ws2[wid] = s2; }
  __syncthreads();
  const float mean = (ws[0] + ws[1] + ws[2] + ws[3]) * (1.f / DINNER);
  const float m2 = (ws2[0] + ws2[1] + ws2[2] + ws2[3]) * (1.f / DINNER);
  const float rstd = rsqrtf(m2 - mean * mean + 1e-5f);
  const float4 w0 = *(const float4*)(lnw + t * 8);
  const float4 w1 = *(const float4*)(lnw + t * 8 + 4);
  const float4 b0 = *(const float4*)(lnb + t * 8);
  const float4 b1 = *(const float4*)(lnb + t * 8 + 4);
  const float wv[8] = {w0.x, w0.y, w0.z, w0.w, w1.x, w1.y, w1.z, w1.w};
  const float bv[8] = {b0.x, b0.y, b0.z, b0.w, b1.x, b1.y, b1.z, b1.w};
  short8 o;
#pragma unroll
  for (int j = 0; j < 8; ++j) {
    const float zn = b2f(zv8[j]);
    const float gate = zn / (1.f + __expf(-zn));
    o[j] = (short)f2b(((v[j] - mean) * rstd * wv[j] + bv[j]) * gate);
  }
  *(short8*)(out + (size_t)tok * DINNER + t * 8) = o;
}

// ---------------------------------------------------------------------------
extern "C" void kernel_launch(void* const* d_in, const int* in_sizes, int n_in,
                              void* d_out, int out_size, void* d_ws, size_t ws_size,
                              hipStream_t stream) {
  const float* hidden = (const float*)d_in[0];
  const float* in_proj_w = (const float*)d_in[1];
  const float* conv_w = (const float*)d_in[2];
  const float* conv_b = (const float*)d_in[3];
  const float* A_log = (const float*)d_in[4];
  const float* dt_w = (const float*)d_in[5];
  const float* dt_b = (const float*)d_in[6];
  const float* B_w = (const float*)d_in[7];
  const float* C_w = (const float*)d_in[8];
  const float* Dv = (const float*)d_in[9];
  const float* ln_w = (const float*)d_in[10];
  const float* ln_b = (const float*)d_in[11];
  const float* out_proj_w = (const float*)d_in[12];

  float* out = (float*)d_out;
  float* f = (float*)d_ws;
  const size_t M1 = 1u << 20;

  // workspace layout (float-offset units):
  bf16u* xzb    = (bf16u*)(f + 0);            // [0,4M)   xz bf16 (8M elems)
  bf16u* xcb    = (bf16u*)(f + 4 * M1);       // [4M,6M)  conv out bf16
  bf16u* BCb    = (bf16u*)(f + 6 * M1);       // [6M,10M) fused B/C proj out
  bf16u* wBCb   = (bf16u*)(f + 10 * M1);      // [10M,14M) fused B/C weights (dead after BC gemm)
  bf16u* ybb    = (bf16u*)(f + 10 * M1);      // [10M,12M) y_intra bf16 (after wBCb dead)
  float* outp0  = f + 10 * M1;                // [10M,12M) out partial 0 (after ybb dead)
  float* outp1  = f + 12 * M1;                // [12M,14M)
  bf16u* wInb   = (bf16u*)(f + 14 * M1);      // [14M,16M) (dead after in_proj)
  bf16u* hiddenb= (bf16u*)(f + 16 * M1);      // [16M,17M) (dead after in_proj)
  bf16u* wdtb   = (bf16u*)(f + 17 * M1);      // [17M,+32K) (dead after dt gemm)
  float* Sbuf   = f + 14 * M1;                // [14M,18M) (after wInb/hiddenb/wdtb dead)
  bf16u* ygb    = (bf16u*)(f + 14 * M1);      // [14M,16M) (after Sbuf dead)
  bf16u* yscb   = (bf16u*)(f + 16 * M1);      // [16M,18M) (after Sbuf dead)
  bf16u* Hprevb = (bf16u*)(f + 18 * M1);      // [18M,20M)
  bf16u* wOb    = (bf16u*)(f + 20 * M1);      // [20M,21M)
  float* dtbuf  = f + 21 * M1;                // [21M,+64K)
  float* rbuf   = f + 21 * M1 + 65536;        // [+64K]
  float* lambuf = f + 21 * M1 + 131072;       // [+1K]

  float* hf = out + OUT_ELEMS;

  // 0. conversions to bf16
  cvt_bf16<<<1024, 256, 0, stream>>>(hidden, hiddenb, 2 * M1);
  cvt_bf16<<<2048, 256, 0, stream>>>(in_proj_w, wInb, 4 * M1);
  cvt_bf16<<<2048, 256, 0, stream>>>(B_w, wBCb, 4 * M1);
  cvt_bf16<<<2048, 256, 0, stream>>>(C_w, wBCb + 4 * M1, 4 * M1);  // FIXED: elem offset 4M
  cvt_bf16<<<1024, 256, 0, stream>>>(out_proj_w, wOb, 2 * M1);
  cvt_bf16<<<32, 256, 0, stream>>>(dt_w, wdtb, NHEADS * DINNER);

  // 1. xz = hidden @ in_proj_w^T  [2048 x 4096], K=1024  (bf16 out)
  gemm_mfma<bf16u><<<dim3(32, 16, 1), 256, 0, stream>>>(
      hiddenb, wInb, xzb, NTOK, 2 * DINNER, DMODEL, DMODEL, DMODEL, 0);
  // 2. conv + SiLU -> xcb (bf16)
  conv_silu<<<2048, 256, 0, stream>>>(xzb, conv_w, conv_b, xcb);
  // 3. dt_raw = xc @ dt_w^T  [2048 x 32], K=2048 (f32 out)
  gemm_mfma<float><<<dim3(1, 16, 1), 256, 0, stream>>>(
      xcb, wdtb, dtbuf, NTOK, NHEADS, DINNER, DINNER, DINNER, 0);
  // 4. fused B/C projection: [2048 x 4096], K=2048 (bf16 out)
  gemm_mfma<bf16u><<<dim3(32, 16, 1), 256, 0, stream>>>(
      xcb, wBCb, BCb, NTOK, 2 * DINNER, DINNER, DINNER, DINNER, 0);
  // 5. dt = softplus(dt_raw + dt_b)
  dt_act<<<(NTOK * NHEADS) / 256, 256, 0, stream>>>(dtbuf, dt_b);
  // 6a. per-chunk intra + states
  chunk_intra<<<BATCH * NHEADS * NCHUNK, 256, 0, stream>>>(
      xcb, BCb, dtbuf, A_log, ybb, Sbuf, rbuf, lambuf);
  // 6b. inter-chunk scan (also writes h_final)
  chunk_scan<<<BATCH * NHEADS, 256, 0, stream>>>(Sbuf, lambuf, Hprevb, hf);
  // 6c. combine -> y (bf16)
  chunk_inter<<<BATCH * NHEADS * NCHUNK, 256, 0, stream>>>(
      BCb, Hprevb, xcb, ybb, rbuf, Dv, yscb);
  // 7. LN + gate -> ygb (bf16)
  ln_gate<<<NTOK, 256, 0, stream>>>(yscb, xzb, ln_w, ln_b, ygb);
  // 8. out = yg @ out_proj_w^T  [2048 x 1024], K=2048, split-K=2 (f32 partials)
  gemm_mfma<float><<<dim3(8, 16, 2), 256, 0, stream>>>(
      ygb, wOb, outp0, NTOK, DMODEL, DINNER / 2, DINNER, DINNER,
      (size_t)2 * M1);
  add_f32<<<2048, 256, 0, stream>>>(outp0, outp1, out, OUT_ELEMS);
}

// Round 6
// 204.606 us; speedup vs baseline: 7.5842x; 1.1226x over previous
//
#include <hip/hip_runtime.h>
#include <math.h>

#define BATCH 2
#define SEQLEN 1024
#define DMODEL 1024
#define DINNER 2048
#define NHEADS 32
#define HEADDIM 64
#define DSTATE 64
#define NTOK (BATCH * SEQLEN)                 // 2048
#define OUT_ELEMS (BATCH * SEQLEN * DMODEL)   // 2097152
#define NCHUNK 16                             // chunks per sequence (Q=64)
#define LDP 72                                // padded LDS stride (bf16 elems)

typedef unsigned short bf16u;
typedef __attribute__((ext_vector_type(8))) short short8;
typedef __attribute__((ext_vector_type(4))) float f32x4;

__device__ __forceinline__ float b2f(short u) {
  return __uint_as_float(((unsigned)(unsigned short)u) << 16);
}
__device__ __forceinline__ unsigned short f2b(float f) {
  unsigned u = __float_as_uint(f);
  u += 0x7fff + ((u >> 16) & 1);   // RNE
  return (unsigned short)(u >> 16);
}

__device__ __forceinline__ void gload16(const void* g, void* l) {
  __builtin_amdgcn_global_load_lds(
      (const __attribute__((address_space(1))) unsigned int*)g,
      (__attribute__((address_space(3))) unsigned int*)l, 16, 0, 0);
}

__device__ __forceinline__ void stv(float* p, float v) { *p = v; }
__device__ __forceinline__ void stv(bf16u* p, float v) { *p = f2b(v); }

// ---------------------------------------------------------------------------
// f32 -> bf16 conversion, 8 elems/thread
// ---------------------------------------------------------------------------
__global__ __launch_bounds__(256) void cvt_bf16(const float* __restrict__ in,
                                                bf16u* __restrict__ out, int n) {
  const int i = (blockIdx.x * 256 + threadIdx.x) * 8;
  if (i >= n) return;
  const float4 a = *(const float4*)(in + i);
  const float4 b = *(const float4*)(in + i + 4);
  short8 o;
  o[0] = f2b(a.x); o[1] = f2b(a.y); o[2] = f2b(a.z); o[3] = f2b(a.w);
  o[4] = f2b(b.x); o[5] = f2b(b.y); o[6] = f2b(b.z); o[7] = f2b(b.w);
  *(short8*)(out + i) = o;
}

// ---------------------------------------------------------------------------
// bf16 MFMA GEMM:  C[m,n] = sum_k A[m][k+kbase] * B[n][k+kbase], f32 accum.
// Tile 128x128, BK=32, 256 threads (4 waves, 2x2 of 64x64).
// Triple-buffered LDS, prefetch distance 2, counted vmcnt (never 0 mid-loop).
// LDS bank-spread swizzle: 16B slot (r,kq) stored at slot r*4 + (kq^((r>>2)&3)).
// Write side realizes this by permuting the per-lane GLOBAL kc (LDS dest stays
// linear, required by global_load_lds); read side applies the same XOR.
// grid.z = split-K slices; slice z handles k in [z*Ksub, (z+1)*Ksub),
// writes to C + z*zstrideC.  lda/ldb are row strides of A/B.
// ---------------------------------------------------------------------------
template <typename OutT>
__global__ __launch_bounds__(256) void gemm_mfma(
    const bf16u* __restrict__ A, const bf16u* __restrict__ B,
    OutT* __restrict__ C, int M, int N, int Ksub, int lda, int ldb,
    size_t zstrideC) {
  __shared__ bf16u sA[3][128 * 32];
  __shared__ bf16u sB[3][128 * 32];
  const int t = threadIdx.x;
  const int lane = t & 63, wave = t >> 6;
  const int bm = blockIdx.y * 128, bn = blockIdx.x * 128;
  const int wr = wave >> 1, wc = wave & 1;
  const int kbase = blockIdx.z * Ksub;
  OutT* Cz = C + (size_t)blockIdx.z * zstrideC;

  const int ra0 = bm + (t >> 2), ra1 = bm + 64 + (t >> 2);
  int rb0 = bn + (t >> 2), rb1 = bn + 64 + (t >> 2);
  rb0 = rb0 < N ? rb0 : N - 1;
  rb1 = rb1 < N ? rb1 : N - 1;
  // swizzled source k-column: slot s=t holds global kq = (s&3) ^ ((s>>4)&3)
  const int kc = (((t & 3) ^ ((t >> 4) & 3))) * 8;

  const bf16u* Ap0 = A + (size_t)ra0 * lda + kbase + kc;
  const bf16u* Ap1 = A + (size_t)ra1 * lda + kbase + kc;
  const bf16u* Bp0 = B + (size_t)rb0 * ldb + kbase + kc;
  const bf16u* Bp1 = B + (size_t)rb1 * ldb + kbase + kc;
  const int ldsoff = (wave * 64) * 8;

#define STAGE(buf, k0)                                   \
  do {                                                   \
    gload16(Ap0 + (k0), sA[buf] + ldsoff);               \
    gload16(Ap1 + (k0), sA[buf] + 2048 + ldsoff);        \
    gload16(Bp0 + (k0), sB[buf] + ldsoff);               \
    gload16(Bp1 + (k0), sB[buf] + 2048 + ldsoff);        \
  } while (0)

  const f32x4 zero = {0.f, 0.f, 0.f, 0.f};
  f32x4 acc[4][4];
#pragma unroll
  for (int m = 0; m < 4; ++m)
#pragma unroll
    for (int n = 0; n < 4; ++n) acc[m][n] = zero;

  const int ln15 = lane & 15, kq = lane >> 4;
  // read-side swizzle: sel = (row>>2)&3 = (ln15>>2)&3 (uniform over m,n frags)
  const int kswz = ((kq ^ ((ln15 >> 2) & 3))) * 8;
  const int nt = Ksub >> 5;

  STAGE(0, 0);
  STAGE(1, 32);
  int curb = 0;
  for (int it = 0; it < nt; ++it) {
    if (it + 2 < nt) {
      const int nb = (it + 2) % 3;
      STAGE(nb, (it + 2) * 32);
      asm volatile("s_waitcnt vmcnt(8)" ::: "memory");
    } else if (it + 1 < nt) {
      asm volatile("s_waitcnt vmcnt(4)" ::: "memory");
    } else {
      asm volatile("s_waitcnt vmcnt(0)" ::: "memory");
    }
    __builtin_amdgcn_s_barrier();
    const bf16u* pA = sA[curb];
    const bf16u* pB = sB[curb];
    short8 af[4], bfr[4];
#pragma unroll
    for (int m = 0; m < 4; ++m)
      af[m] = *(const short8*)&pA[(wr * 64 + m * 16 + ln15) * 32 + kswz];
#pragma unroll
    for (int n = 0; n < 4; ++n)
      bfr[n] = *(const short8*)&pB[(wc * 64 + n * 16 + ln15) * 32 + kswz];
    __builtin_amdgcn_s_setprio(1);
#pragma unroll
    for (int m = 0; m < 4; ++m)
#pragma unroll
      for (int n = 0; n < 4; ++n)
        acc[m][n] = __builtin_amdgcn_mfma_f32_16x16x32_bf16(af[m], bfr[n], acc[m][n], 0, 0, 0);
    __builtin_amdgcn_s_setprio(0);
    asm volatile("s_waitcnt lgkmcnt(0)" ::: "memory");
    __builtin_amdgcn_s_barrier();
    curb = (curb == 2) ? 0 : curb + 1;
  }
#undef STAGE

  const int rbase = bm + wr * 64, cbase = bn + wc * 64;
#pragma unroll
  for (int m = 0; m < 4; ++m) {
#pragma unroll
    for (int n = 0; n < 4; ++n) {
      const int col = cbase + n * 16 + ln15;
      if (col < N) {
#pragma unroll
        for (int r = 0; r < 4; ++r) {
          const int row = rbase + m * 16 + kq * 4 + r;
          stv(&Cz[(size_t)row * N + col], acc[m][n][r]);
        }
      }
    }
  }
}

// ---------------------------------------------------------------------------
// out = a + b (f32), 4 elems/thread
// ---------------------------------------------------------------------------
__global__ __launch_bounds__(256) void add_f32(const float* __restrict__ a,
                                               const float* __restrict__ b,
                                               float* __restrict__ o, int n) {
  const int i = (blockIdx.x * 256 + threadIdx.x) * 4;
  if (i >= n) return;
  const float4 x = *(const float4*)(a + i);
  const float4 y = *(const float4*)(b + i);
  *(float4*)(o + i) = make_float4(x.x + y.x, x.y + y.y, x.z + y.z, x.w + y.w);
}

// ---------------------------------------------------------------------------
// Depthwise causal conv (width 4) + bias + SiLU. bf16 in/out.
// ---------------------------------------------------------------------------
__global__ __launch_bounds__(256) void conv_silu(
    const bf16u* __restrict__ xzb, const float* __restrict__ cw,
    const float* __restrict__ cb, bf16u* __restrict__ xcb) {
  const int i = blockIdx.x * 256 + threadIdx.x;  // 0..512K
  const int c8 = (i & 255) * 8;
  const int tok = i >> 8;
  const int l = tok & (SEQLEN - 1);
  const bf16u* xp = xzb + (size_t)tok * (2 * DINNER) + c8;
  const short8 zer = {0, 0, 0, 0, 0, 0, 0, 0};
  const short8 x0 = *(const short8*)xp;
  const short8 x1 = (l >= 1) ? *(const short8*)(xp - 1 * (2 * DINNER)) : zer;
  const short8 x2 = (l >= 2) ? *(const short8*)(xp - 2 * (2 * DINNER)) : zer;
  const short8 x3 = (l >= 3) ? *(const short8*)(xp - 3 * (2 * DINNER)) : zer;
  short8 ob;
#pragma unroll
  for (int j = 0; j < 8; ++j) {
    const float4 w = *(const float4*)(cw + (c8 + j) * 4);
    float acc = cb[c8 + j] + w.w * b2f(x0[j]);
    acc += w.z * b2f(x1[j]);
    acc += w.y * b2f(x2[j]);
    acc += w.x * b2f(x3[j]);
    const float s = acc / (1.f + __expf(-acc));
    ob[j] = (short)f2b(s);
  }
  *(short8*)(xcb + (size_t)tok * DINNER + c8) = ob;
}

// ---------------------------------------------------------------------------
// dt activation: sum 4 split-K partials, + dt_b, softplus. Writes final dt to
// partial-0 slot (dtb base).
// ---------------------------------------------------------------------------
__global__ __launch_bounds__(256) void dt_act(float* __restrict__ dtb,
                                              const float* __restrict__ dt_b) {
  const int i = blockIdx.x * 256 + threadIdx.x;
  if (i >= NTOK * NHEADS) return;
  const float v = dtb[i] + dtb[i + 65536] + dtb[i + 131072] + dtb[i + 196608] +
                  dt_b[i & (NHEADS - 1)];
  dtb[i] = (v > 20.f) ? v : log1pf(expf(v));
}

// ---------------------------------------------------------------------------
// Chunked SSD, stage 1 (per chunk): decay cumsum, G=C@B^T masked -> P,
// Y_intra = P@X (bf16 out), S = X^T diag(w) B. One block per (b,h,c).
// B/C come fused in BCb [NTOK, 4096]: cols [0,2048)=B, [2048,4096)=C.
// ---------------------------------------------------------------------------
__global__ __launch_bounds__(256) void chunk_intra(
    const bf16u* __restrict__ xcb, const bf16u* __restrict__ BCb,
    const float* __restrict__ dtb, const float* __restrict__ A_log,
    bf16u* __restrict__ ybb, float* __restrict__ Sbuf,
    float* __restrict__ rbuf, float* __restrict__ lambuf) {
  __shared__ bf16u sC[64 * LDP], sB[64 * LDP], sXT[64 * LDP];
  __shared__ bf16u sWBT[64 * LDP], sP[64 * LDP];
  __shared__ float sS[64], sDt[64], sW[64];

  const int blk = blockIdx.x;
  const int bh = blk >> 4, c = blk & (NCHUNK - 1);
  const int b = bh >> 5, h = bh & (NHEADS - 1);
  const int t = threadIdx.x, lane = t & 63, wave = t >> 6;
  const int t0 = b * SEQLEN + c * 64;
  const size_t rowbase = (size_t)t0 * DINNER + h * 64;        // x
  const size_t rowBC = (size_t)t0 * 4096 + h * 64;            // fused B/C

  // ---- P0: staging + decay scan ----
  if (wave == 0) {
    const float dtv = dtb[(size_t)(t0 + lane) * NHEADS + h];
    const float Ah = -__expf(A_log[h]);
    float s = Ah * dtv;
#pragma unroll
    for (int off = 1; off < 64; off <<= 1) {
      const float o = __shfl_up(s, off);
      if (lane >= off) s += o;
    }
    const float stot = __shfl(s, 63);
    sS[lane] = s;
    sDt[lane] = dtv;
    sW[lane] = __expf(stot - s) * dtv;
    rbuf[(size_t)blk * 64 + lane] = __expf(s);
    if (lane == 0) lambuf[blk] = __expf(stot);
  } else if (wave == 1) {
#pragma unroll
    for (int it = 0; it < 8; ++it) {
      const int slot = it * 64 + lane;
      const int r = slot >> 3, c8 = (slot & 7) * 8;
      *(short8*)&sC[r * LDP + c8] =
          *(const short8*)&BCb[rowBC + 2048 + (size_t)r * 4096 + c8];
    }
  } else if (wave == 2) {
#pragma unroll
    for (int it = 0; it < 8; ++it) {
      const int slot = it * 64 + lane;
      const int r = slot >> 3, c8 = (slot & 7) * 8;
      *(short8*)&sB[r * LDP + c8] =
          *(const short8*)&BCb[rowBC + (size_t)r * 4096 + c8];
    }
  } else {
#pragma unroll
    for (int it = 0; it < 8; ++it) {
      const int slot = it * 64 + lane;
      const int j = slot >> 3, p0 = (slot & 7) * 8;
      const short8 v = *(const short8*)&xcb[rowbase + (size_t)j * DINNER + p0];
#pragma unroll
      for (int k = 0; k < 8; ++k) sXT[(p0 + k) * LDP + j] = v[k];
    }
  }
  __syncthreads();

  // ---- P1: WBT[n][j] = w_j * B[j][n]; G mfma + mask -> P ----
  {
    const int j = t >> 2, n0 = (t & 3) * 16;
    const float wj = sW[j];
#pragma unroll
    for (int k = 0; k < 16; ++k)
      sWBT[(n0 + k) * LDP + j] = f2b(wj * b2f(sB[j * LDP + n0 + k]));
  }
  const int ln15 = lane & 15, kq = lane >> 4;
  const int i0 = wave * 16;
  const f32x4 zero = {0.f, 0.f, 0.f, 0.f};
  {
    f32x4 g[4];
#pragma unroll
    for (int jf = 0; jf < 4; ++jf) g[jf] = zero;
#pragma unroll
    for (int k0 = 0; k0 < 64; k0 += 32) {
      const short8 a = *(const short8*)&sC[(i0 + ln15) * LDP + k0 + kq * 8];
#pragma unroll
      for (int jf = 0; jf < 4; ++jf) {
        const short8 bb = *(const short8*)&sB[(jf * 16 + ln15) * LDP + k0 + kq * 8];
        g[jf] = __builtin_amdgcn_mfma_f32_16x16x32_bf16(a, bb, g[jf], 0, 0, 0);
      }
    }
#pragma unroll
    for (int jf = 0; jf < 4; ++jf) {
      const int j = jf * 16 + ln15;
      const float sj = sS[j], dtj = sDt[j];
#pragma unroll
      for (int r = 0; r < 4; ++r) {
        const int i = i0 + kq * 4 + r;
        const float v = (j <= i) ? g[jf][r] * __expf(sS[i] - sj) * dtj : 0.f;
        sP[i * LDP + j] = f2b(v);
      }
    }
  }
  __syncthreads();

  // ---- P2: Y_intra = P @ XT^T ; S = XT @ WBT^T ----
  f32x4 yi[4], ss[4];
#pragma unroll
  for (int f = 0; f < 4; ++f) { yi[f] = zero; ss[f] = zero; }
#pragma unroll
  for (int k0 = 0; k0 < 64; k0 += 32) {
    const short8 ap = *(const short8*)&sP[(i0 + ln15) * LDP + k0 + kq * 8];
    const short8 ax = *(const short8*)&sXT[(i0 + ln15) * LDP + k0 + kq * 8];
#pragma unroll
    for (int f = 0; f < 4; ++f) {
      const short8 bx = *(const short8*)&sXT[(f * 16 + ln15) * LDP + k0 + kq * 8];
      const short8 bw = *(const short8*)&sWBT[(f * 16 + ln15) * LDP + k0 + kq * 8];
      yi[f] = __builtin_amdgcn_mfma_f32_16x16x32_bf16(ap, bx, yi[f], 0, 0, 0);
      ss[f] = __builtin_amdgcn_mfma_f32_16x16x32_bf16(ax, bw, ss[f], 0, 0, 0);
    }
  }
  bf16u* yb = ybb + (size_t)blk * 4096;
  float* sb = Sbuf + (size_t)blk * 4096;
#pragma unroll
  for (int f = 0; f < 4; ++f) {
#pragma unroll
    for (int r = 0; r < 4; ++r) {
      const int row = i0 + kq * 4 + r;
      const int col = f * 16 + ln15;
      yb[row * 64 + col] = f2b(yi[f][r]);
      sb[row * 64 + col] = ss[f][r];
    }
  }
}

// ---------------------------------------------------------------------------
// Chunked SSD, stage 2: inter-chunk state scan (16 steps, scalar decay).
// ---------------------------------------------------------------------------
__global__ __launch_bounds__(256) void chunk_scan(
    const float* __restrict__ Sbuf, const float* __restrict__ lambuf,
    bf16u* __restrict__ Hprevb, float* __restrict__ hf) {
  const int bh = blockIdx.x;
  const int t = threadIdx.x;
  const int e0 = t * 16;
  float H[16];
#pragma unroll
  for (int j = 0; j < 16; ++j) H[j] = 0.f;

  float4 cur[4];
  float lam;
  {
    const float4* sp = (const float4*)(Sbuf + (size_t)(bh * NCHUNK) * 4096 + e0);
#pragma unroll
    for (int q = 0; q < 4; ++q) cur[q] = sp[q];
    lam = lambuf[bh * NCHUNK];
  }
  for (int c = 0; c < NCHUNK; ++c) {
    float4 nxt[4];
    float lamn = 0.f;
    if (c < NCHUNK - 1) {
      const float4* sp = (const float4*)(Sbuf + (size_t)(bh * NCHUNK + c + 1) * 4096 + e0);
#pragma unroll
      for (int q = 0; q < 4; ++q) nxt[q] = sp[q];
      lamn = lambuf[bh * NCHUNK + c + 1];
    }
    short8 o0, o1;
#pragma unroll
    for (int j = 0; j < 8; ++j) o0[j] = (short)f2b(H[j]);
#pragma unroll
    for (int j = 0; j < 8; ++j) o1[j] = (short)f2b(H[8 + j]);
    *(short8*)&Hprevb[(size_t)(bh * NCHUNK + c) * 4096 + e0] = o0;
    *(short8*)&Hprevb[(size_t)(bh * NCHUNK + c) * 4096 + e0 + 8] = o1;
#pragma unroll
    for (int q = 0; q < 4; ++q) {
      H[q * 4 + 0] = lam * H[q * 4 + 0] + cur[q].x;
      H[q * 4 + 1] = lam * H[q * 4 + 1] + cur[q].y;
      H[q * 4 + 2] = lam * H[q * 4 + 2] + cur[q].z;
      H[q * 4 + 3] = lam * H[q * 4 + 3] + cur[q].w;
    }
#pragma unroll
    for (int q = 0; q < 4; ++q) cur[q] = nxt[q];
    lam = lamn;
  }
  float* hp = hf + (size_t)bh * 4096 + e0;
#pragma unroll
  for (int q = 0; q < 4; ++q)
    *(float4*)(hp + q * 4) =
        make_float4(H[q * 4], H[q * 4 + 1], H[q * 4 + 2], H[q * 4 + 3]);
}

// ---------------------------------------------------------------------------
// Chunked SSD, stage 3 (per chunk): Y = Y_intra + r_i * C @ Hprev^T + D*x.
// ---------------------------------------------------------------------------
__global__ __launch_bounds__(256) void chunk_inter(
    const bf16u* __restrict__ BCb, const bf16u* __restrict__ Hprevb,
    const bf16u* __restrict__ xcb, const bf16u* __restrict__ ybb,
    const float* __restrict__ rbuf, const float* __restrict__ Dvec,
    bf16u* __restrict__ yout) {
  __shared__ bf16u sC[64 * LDP], sH[64 * LDP];
  __shared__ float sR[64];
  const int blk = blockIdx.x;
  const int bh = blk >> 4, c = blk & (NCHUNK - 1);
  const int b = bh >> 5, h = bh & (NHEADS - 1);
  const int t = threadIdx.x, lane = t & 63, wave = t >> 6;
  const int t0 = b * SEQLEN + c * 64;
  const size_t rowbase = (size_t)t0 * DINNER + h * 64;
  const size_t rowBC = (size_t)t0 * 4096 + h * 64;

#pragma unroll
  for (int it = 0; it < 2; ++it) {
    const int slot = it * 256 + t;          // 0..511
    const int r = slot >> 3, c8 = (slot & 7) * 8;
    *(short8*)&sC[r * LDP + c8] =
        *(const short8*)&BCb[rowBC + 2048 + (size_t)r * 4096 + c8];
    *(short8*)&sH[r * LDP + c8] =
        *(const short8*)&Hprevb[(size_t)blk * 4096 + slot * 8];
  }
  if (t < 64) sR[t] = rbuf[(size_t)blk * 64 + t];
  __syncthreads();

  const int ln15 = lane & 15, kq = lane >> 4;
  const int i0 = wave * 16;
  const f32x4 zero = {0.f, 0.f, 0.f, 0.f};
  f32x4 acc[4];
#pragma unroll
  for (int f = 0; f < 4; ++f) acc[f] = zero;
#pragma unroll
  for (int k0 = 0; k0 < 64; k0 += 32) {
    const short8 a = *(const short8*)&sC[(i0 + ln15) * LDP + k0 + kq * 8];
#pragma unroll
    for (int f = 0; f < 4; ++f) {
      const short8 bh8 = *(const short8*)&sH[(f * 16 + ln15) * LDP + k0 + kq * 8];
      acc[f] = __builtin_amdgcn_mfma_f32_16x16x32_bf16(a, bh8, acc[f], 0, 0, 0);
    }
  }
  const float Dh = Dvec[h];
  const bf16u* yb = ybb + (size_t)blk * 4096;
#pragma unroll
  for (int f = 0; f < 4; ++f) {
    const int p = f * 16 + ln15;
#pragma unroll
    for (int r = 0; r < 4; ++r) {
      const int i = i0 + kq * 4 + r;
      const float xv = b2f((short)xcb[rowbase + (size_t)i * DINNER + p]);
      const float y = b2f((short)yb[i * 64 + p]) + sR[i] * acc[f][r] + Dh * xv;
      yout[rowbase + (size_t)i * DINNER + p] = f2b(y);
    }
  }
}

// ---------------------------------------------------------------------------
// LayerNorm(2048) + SiLU(z) gate. bf16 y/z in, bf16 out. One block per token.
// ---------------------------------------------------------------------------
__global__ __launch_bounds__(256) void ln_gate(
    const bf16u* __restrict__ y, const bf16u* __restrict__ xzb,
    const float* __restrict__ lnw, const float* __restrict__ lnb,
    bf16u* __restrict__ out) {
  const int tok = blockIdx.x;
  const int t = threadIdx.x;
  const short8 yv8 = *(const short8*)(y + (size_t)tok * DINNER + t * 8);
  const short8 zv8 = *(const short8*)(xzb + (size_t)tok * (2 * DINNER) + DINNER + t * 8);
  float v[8];
  float s = 0.f, s2 = 0.f;
#pragma unroll
  for (int j = 0; j < 8; ++j) {
    v[j] = b2f(yv8[j]);
    s += v[j];
    s2 += v[j] * v[j];
  }
#pragma unroll
  for (int off = 32; off > 0; off >>= 1) {
    s += __shfl_down(s, off);
    s2 += __shfl_down(s2, off);
  }
  __shared__ float ws[4], ws2[4];
  const int wid = t >> 6;
  if ((t & 63) == 0) { ws[wid] = s; ws2[wid] = s2; }
  __syncthreads();
  const float mean = (ws[0] + ws[1] + ws[2] + ws[3]) * (1.f / DINNER);
  const float m2 = (ws2[0] + ws2[1] + ws2[2] + ws2[3]) * (1.f / DINNER);
  const float rstd = rsqrtf(m2 - mean * mean + 1e-5f);
  const float4 w0 = *(const float4*)(lnw + t * 8);
  const float4 w1 = *(const float4*)(lnw + t * 8 + 4);
  const float4 b0 = *(const float4*)(lnb + t * 8);
  const float4 b1 = *(const float4*)(lnb + t * 8 + 4);
  const float wv[8] = {w0.x, w0.y, w0.z, w0.w, w1.x, w1.y, w1.z, w1.w};
  const float bv[8] = {b0.x, b0.y, b0.z, b0.w, b1.x, b1.y, b1.z, b1.w};
  short8 o;
#pragma unroll
  for (int j = 0; j < 8; ++j) {
    const float zn = b2f(zv8[j]);
    const float gate = zn / (1.f + __expf(-zn));
    o[j] = (short)f2b(((v[j] - mean) * rstd * wv[j] + bv[j]) * gate);
  }
  *(short8*)(out + (size_t)tok * DINNER + t * 8) = o;
}

// ---------------------------------------------------------------------------
extern "C" void kernel_launch(void* const* d_in, const int* in_sizes, int n_in,
                              void* d_out, int out_size, void* d_ws, size_t ws_size,
                              hipStream_t stream) {
  const float* hidden = (const float*)d_in[0];
  const float* in_proj_w = (const float*)d_in[1];
  const float* conv_w = (const float*)d_in[2];
  const float* conv_b = (const float*)d_in[3];
  const float* A_log = (const float*)d_in[4];
  const float* dt_w = (const float*)d_in[5];
  const float* dt_b = (const float*)d_in[6];
  const float* B_w = (const float*)d_in[7];
  const float* C_w = (const float*)d_in[8];
  const float* Dv = (const float*)d_in[9];
  const float* ln_w = (const float*)d_in[10];
  const float* ln_b = (const float*)d_in[11];
  const float* out_proj_w = (const float*)d_in[12];

  float* out = (float*)d_out;
  float* f = (float*)d_ws;
  const size_t M1 = 1u << 20;

  // workspace layout (float-offset units):
  bf16u* xzb    = (bf16u*)(f + 0);            // [0,4M)   xz bf16 (8M elems)
  bf16u* xcb    = (bf16u*)(f + 4 * M1);       // [4M,6M)  conv out bf16
  bf16u* BCb    = (bf16u*)(f + 6 * M1);       // [6M,10M) fused B/C proj out
  bf16u* wBCb   = (bf16u*)(f + 10 * M1);      // [10M,14M) fused B/C weights (dead after BC gemm)
  bf16u* ybb    = (bf16u*)(f + 10 * M1);      // [10M,12M) y_intra bf16 (after wBCb dead)
  float* outp0  = f + 10 * M1;                // [10M,12M) out partial 0 (after ybb dead)
  float* outp1  = f + 12 * M1;                // [12M,14M)
  bf16u* wInb   = (bf16u*)(f + 14 * M1);      // [14M,16M) (dead after in_proj)
  bf16u* hiddenb= (bf16u*)(f + 16 * M1);      // [16M,17M) (dead after in_proj)
  bf16u* wdtb   = (bf16u*)(f + 17 * M1);      // [17M,+32K) (dead after dt gemm)
  float* Sbuf   = f + 14 * M1;                // [14M,18M) (after wInb/hiddenb/wdtb dead)
  bf16u* ygb    = (bf16u*)(f + 14 * M1);      // [14M,16M) (after Sbuf dead)
  bf16u* yscb   = (bf16u*)(f + 16 * M1);      // [16M,18M) (after Sbuf dead)
  bf16u* Hprevb = (bf16u*)(f + 18 * M1);      // [18M,20M)
  bf16u* wOb    = (bf16u*)(f + 20 * M1);      // [20M,21M)
  float* dtbuf  = f + 21 * M1;                // [21M,+256K) 4 split-K partials
  float* rbuf   = f + 21 * M1 + 262144;       // [+64K]
  float* lambuf = f + 21 * M1 + 327680;       // [+1K]

  float* hf = out + OUT_ELEMS;

  // 0. conversions to bf16
  cvt_bf16<<<1024, 256, 0, stream>>>(hidden, hiddenb, 2 * M1);
  cvt_bf16<<<2048, 256, 0, stream>>>(in_proj_w, wInb, 4 * M1);
  cvt_bf16<<<2048, 256, 0, stream>>>(B_w, wBCb, 4 * M1);
  cvt_bf16<<<2048, 256, 0, stream>>>(C_w, wBCb + 4 * M1, 4 * M1);
  cvt_bf16<<<1024, 256, 0, stream>>>(out_proj_w, wOb, 2 * M1);
  cvt_bf16<<<32, 256, 0, stream>>>(dt_w, wdtb, NHEADS * DINNER);

  // 1. xz = hidden @ in_proj_w^T  [2048 x 4096], K=1024  (bf16 out)
  gemm_mfma<bf16u><<<dim3(32, 16, 1), 256, 0, stream>>>(
      hiddenb, wInb, xzb, NTOK, 2 * DINNER, DMODEL, DMODEL, DMODEL, 0);
  // 2. conv + SiLU -> xcb (bf16)
  conv_silu<<<2048, 256, 0, stream>>>(xzb, conv_w, conv_b, xcb);
  // 3. dt_raw = xc @ dt_w^T  [2048 x 32], K=2048, split-K=4 (f32 partials)
  gemm_mfma<float><<<dim3(1, 16, 4), 256, 0, stream>>>(
      xcb, wdtb, dtbuf, NTOK, NHEADS, DINNER / 4, DINNER, DINNER,
      (size_t)NTOK * NHEADS);
  // 4. fused B/C projection: [2048 x 4096], K=2048 (bf16 out)
  gemm_mfma<bf16u><<<dim3(32, 16, 1), 256, 0, stream>>>(
      xcb, wBCb, BCb, NTOK, 2 * DINNER, DINNER, DINNER, DINNER, 0);
  // 5. dt = softplus(sum partials + dt_b)
  dt_act<<<(NTOK * NHEADS) / 256, 256, 0, stream>>>(dtbuf, dt_b);
  // 6a. per-chunk intra + states
  chunk_intra<<<BATCH * NHEADS * NCHUNK, 256, 0, stream>>>(
      xcb, BCb, dtbuf, A_log, ybb, Sbuf, rbuf, lambuf);
  // 6b. inter-chunk scan (also writes h_final)
  chunk_scan<<<BATCH * NHEADS, 256, 0, stream>>>(Sbuf, lambuf, Hprevb, hf);
  // 6c. combine -> y (bf16)
  chunk_inter<<<BATCH * NHEADS * NCHUNK, 256, 0, stream>>>(
      BCb, Hprevb, xcb, ybb, rbuf, Dv, yscb);
  // 7. LN + gate -> ygb (bf16)
  ln_gate<<<NTOK, 256, 0, stream>>>(yscb, xzb, ln_w, ln_b, ygb);
  // 8. out = yg @ out_proj_w^T  [2048 x 1024], K=2048, split-K=2 (f32 partials)
  gemm_mfma<float><<<dim3(8, 16, 2), 256, 0, stream>>>(
      ygb, wOb, outp0, NTOK, DMODEL, DINNER / 2, DINNER, DINNER,
      (size_t)2 * M1);
  add_f32<<<2048, 256, 0, stream>>>(outp0, outp1, out, OUT_ELEMS);
}